// Round 2
// baseline (485.749 us; speedup 1.0000x reference)
//
#include <hip/hip_runtime.h>

#define N_NODES 50000
#define N_EDGES 800000
#define C_IN 64
#define HID 3
#define C_OUTC 128
#define ATTR 6
#define K3 192            // HID*C_IN
#define NBK 782           // fine buckets of 64 nodes (dst>>6)
#define NPAD 50048        // NBK*64
#define CAP 1280          // per-bucket seg capacity: mean 1023, +8 sigma
#define CAPP 1792         // per-bucket csr capacity with pad-to-8 (1280+448<=1792, deterministic)
#define EPB 4096          // edges per pass1 block
#define P1B 196           // pass1 blocks per layer

typedef _Float16 half4v __attribute__((ext_vector_type(4)));

// ---------------------------------------------------------------------------
// pass1: bin edges by fine bucket (dst>>6), both layers. (Unchanged.)
// ---------------------------------------------------------------------------
__global__ __launch_bounds__(512)
void pass1(const int* __restrict__ ei0, const int* __restrict__ ei1,
           int* __restrict__ cursor, int2* __restrict__ seg)
{
    __shared__ int s_cnt[NBK], s_ofs[NBK], s_pos[NBK], s_gbase[NBK]; // 12.5 KB
    __shared__ int2 st_es[EPB];                                      // 32 KB
    __shared__ unsigned short st_b[EPB];                             //  8 KB
    __shared__ int wsum[8];
    const int t = threadIdx.x, lane = t & 63, wid = t >> 6;
    const int l = (blockIdx.x >= P1B) ? 1 : 0;
    const int* ei = l ? ei1 : ei0;
    const int base = (blockIdx.x - l * P1B) * EPB;

    for (int i = t; i < NBK; i += 512) s_cnt[i] = 0;
    __syncthreads();

    int src[8], dst[8];
    const int e0 = base + t * 8;
    if (e0 + 7 < N_EDGES) {
        const int4 s0 = *(const int4*)(ei + e0);
        const int4 s1 = *(const int4*)(ei + e0 + 4);
        const int4 d0 = *(const int4*)(ei + N_EDGES + e0);
        const int4 d1 = *(const int4*)(ei + N_EDGES + e0 + 4);
        src[0]=s0.x; src[1]=s0.y; src[2]=s0.z; src[3]=s0.w;
        src[4]=s1.x; src[5]=s1.y; src[6]=s1.z; src[7]=s1.w;
        dst[0]=d0.x; dst[1]=d0.y; dst[2]=d0.z; dst[3]=d0.w;
        dst[4]=d1.x; dst[5]=d1.y; dst[6]=d1.z; dst[7]=d1.w;
    } else {
#pragma unroll
        for (int j = 0; j < 8; ++j) {
            const int e = e0 + j;
            if (e < N_EDGES) { src[j] = ei[e]; dst[j] = ei[N_EDGES + e]; }
            else dst[j] = -1;
        }
    }
#pragma unroll
    for (int j = 0; j < 8; ++j)
        if (dst[j] >= 0) atomicAdd(&s_cnt[dst[j] >> 6], 1);
    __syncthreads();

    // Exclusive block scan of s_cnt[NBK], 2 elements per thread.
    const int i0 = 2 * t, i1 = 2 * t + 1;
    const int v0 = (i0 < NBK) ? s_cnt[i0] : 0;
    const int v1 = (i1 < NBK) ? s_cnt[i1] : 0;
    const int pv = v0 + v1;
    int incl = pv;
#pragma unroll
    for (int off = 1; off < 64; off <<= 1) {
        const int u = __shfl_up(incl, off, 64);
        if (lane >= off) incl += u;
    }
    if (lane == 63) wsum[wid] = incl;
    __syncthreads();
    if (wid == 0) {
        int s = (lane < 8) ? wsum[lane] : 0;
#pragma unroll
        for (int off = 1; off < 8; off <<= 1) {
            const int u = __shfl_up(s, off, 64);
            if (lane >= off) s += u;
        }
        if (lane < 8) wsum[lane] = s;
    }
    __syncthreads();
    const int ex = (wid ? wsum[wid - 1] : 0) + (incl - pv);
    if (i0 < NBK) { s_ofs[i0] = ex;      s_pos[i0] = ex; }
    if (i1 < NBK) { s_ofs[i1] = ex + v0; s_pos[i1] = ex + v0; }
    __syncthreads();

    for (int i = t; i < NBK; i += 512)
        s_gbase[i] = atomicAdd(&cursor[(l << 10) + i], s_cnt[i]);

#pragma unroll
    for (int j = 0; j < 8; ++j) {
        if (dst[j] >= 0) {
            const int b = dst[j] >> 6;
            const int p = atomicAdd(&s_pos[b], 1);
            st_es[p] = make_int2((e0 + j) | ((dst[j] & 63) << 20), src[j]);
            st_b[p]  = (unsigned short)b;
        }
    }
    __syncthreads();

    const int total = (N_EDGES - base < EPB) ? (N_EDGES - base) : EPB;
    for (int j = t; j < total; j += 512) {
        const int b = st_b[j];
        const int g = s_gbase[b] + (j - s_ofs[b]);
        if (g < CAP) seg[(size_t)(l * NBK + b) * CAP + g] = st_es[j];
    }
}

// ---------------------------------------------------------------------------
// pass2: histogram -> padded scan -> node-sorted scatter + sentinel padding.
// (Unchanged.)
// ---------------------------------------------------------------------------
__global__ __launch_bounds__(256)
void pass2(const int* __restrict__ cursor, const int2* __restrict__ seg,
           int2* __restrict__ csr, int2* __restrict__ row_info)
{
    __shared__ int hist[64], cur[64], pex[64];
    const int t = threadIdx.x;
    const int l = (blockIdx.x >= NBK) ? 1 : 0;
    const int fb = blockIdx.x - l * NBK;
    const int S0 = cursor[(l << 10) + fb];
    const int S = (S0 < CAP) ? S0 : CAP;
    const size_t segbase = (size_t)(l * NBK + fb) * CAP;
    const size_t base = (size_t)(l * NBK + fb) * CAPP;
    const int2* segb = seg + segbase;

    if (t < 64) hist[t] = 0;
    __syncthreads();
    for (int i = t; i < S; i += 256)
        atomicAdd(&hist[(segb[i].x >> 20) & 63], 1);
    __syncthreads();

    if (t < 64) {                                             // wave 0 scan
        const int v = hist[t];
        const int pv = (v + 7) & ~7;                          // pad to 8
        int incl = pv;
#pragma unroll
        for (int off = 1; off < 64; off <<= 1) {
            const int u = __shfl_up(incl, off, 64);
            if (t >= off) incl += u;
        }
        const int excl = incl - pv;                           // multiple of 8
        cur[t] = excl;
        pex[t] = excl;
        const int node = fb * 64 + t;
        if (node < N_NODES)
            row_info[l * NPAD + node] = make_int2((int)base + excl, v);
    }
    __syncthreads();

    for (int i = t; i < S; i += 256) {
        const int2 p = segb[i];
        const int dl = (p.x >> 20) & 63;
        const int pos = atomicAdd(&cur[dl], 1);
        csr[base + pos] = p;
    }

    // Fill padding slots (disjoint from scatter region -> no barrier needed).
    if (t < 64) {
        const int v = hist[t];
        const int pv = (v + 7) & ~7;
        for (int p = pex[t] + v; p < pex[t] + pv; ++p)
            csr[base + p] = make_int2(0, N_NODES);            // zero-row sentinel
    }
}

// ---------------------------------------------------------------------------
// xcvt: x fp32 -> bf16 (RNE), plus zeroed sentinel row at index N_NODES.
// ---------------------------------------------------------------------------
#define XW4 ((N_NODES * C_IN) / 4)
#define XW4Z (((N_NODES + 1) * C_IN) / 4)
__global__ __launch_bounds__(256)
void xcvt(const float* __restrict__ x, unsigned short* __restrict__ xb)
{
    const int i = blockIdx.x * 256 + threadIdx.x;             // float4 index
    if (i < XW4) {
        const float4 v = ((const float4*)x)[i];
        ushort4 o;
        unsigned u;
        u = __float_as_uint(v.x); o.x = (unsigned short)((u + 0x7FFF + ((u >> 16) & 1)) >> 16);
        u = __float_as_uint(v.y); o.y = (unsigned short)((u + 0x7FFF + ((u >> 16) & 1)) >> 16);
        u = __float_as_uint(v.z); o.z = (unsigned short)((u + 0x7FFF + ((u >> 16) & 1)) >> 16);
        u = __float_as_uint(v.w); o.w = (unsigned short)((u + 0x7FFF + ((u >> 16) & 1)) >> 16);
        ((ushort4*)xb)[i] = o;
    } else if (i < XW4Z) {
        ((ushort4*)xb)[i] = make_ushort4(0, 0, 0, 0);         // zero row
    }
}

// ---------------------------------------------------------------------------
// phaseB: ONE WAVE PER (layer,node). No LDS, no barriers -> occupancy is
// VGPR-limited (~32 waves/CU vs 12 in the fused version) and degree skew
// no longer idles sibling waves at a barrier. Inner loop identical to R1:
// 8-edge chunks, uniform int4 csr loads, scalarized indices, 8 xb gathers
// in flight. Result row written to global agg as fp16 (error ~3e-4 on out,
// an order below the existing bf16-x error).
// ---------------------------------------------------------------------------
__global__ __launch_bounds__(256)
void phaseB(const unsigned short* __restrict__ xb,
            const float* __restrict__ ea0, const float* __restrict__ ea1,
            const float* __restrict__ Wi0, const float* __restrict__ bi0,
            const float* __restrict__ Wi1, const float* __restrict__ bi1,
            const int2* __restrict__ row_info, const int2* __restrict__ csr,
            _Float16* __restrict__ aggh)
{
    const int t = threadIdx.x, lane = t & 63, wv = t >> 6;
    const int slot = blockIdx.x * 4 + wv;                     // < 2*NPAD
    const int l = (slot >= NPAD) ? 1 : 0;
    const int node = slot - l * NPAD;
    const float* ea = l ? ea1 : ea0;
    const float* Wi = l ? Wi1 : Wi0;
    const float* bi = l ? bi1 : bi0;

    const int col = 3 * lane;
    float w[ATTR][HID], bb[HID];
#pragma unroll
    for (int k = 0; k < ATTR; ++k)
#pragma unroll
        for (int h = 0; h < HID; ++h)
            w[k][h] = Wi[k * K3 + col + h];
#pragma unroll
    for (int h = 0; h < HID; ++h) bb[h] = bi[col + h];

    int2 ri = make_int2(0, 0);
    if (node < N_NODES) ri = row_info[slot];
    const int rb   = __builtin_amdgcn_readfirstlane(ri.x);
    const int cnt8 = __builtin_amdgcn_readfirstlane((ri.y + 7) & ~7);
    const int2* __restrict__ ep = csr + rb;                   // 64B aligned

    float acc0 = 0.f, acc1 = 0.f, acc2 = 0.f;
    for (int i = 0; i < cnt8; i += 8) {
        // 8 csr entries via 4 uniform 16B loads
        const int4 q0 = *(const int4*)(ep + i + 0);
        const int4 q1 = *(const int4*)(ep + i + 2);
        const int4 q2 = *(const int4*)(ep + i + 4);
        const int4 q3 = *(const int4*)(ep + i + 6);
        int se[8], ee[8];
        se[0] = q0.y; ee[0] = q0.x; se[1] = q0.w; ee[1] = q0.z;
        se[2] = q1.y; ee[2] = q1.x; se[3] = q1.w; ee[3] = q1.z;
        se[4] = q2.y; ee[4] = q2.x; se[5] = q2.w; ee[5] = q2.z;
        se[6] = q3.y; ee[6] = q3.x; se[7] = q3.w; ee[7] = q3.z;
#pragma unroll
        for (int j = 0; j < 8; ++j) {
            se[j] = __builtin_amdgcn_readfirstlane(se[j]);
            ee[j] = __builtin_amdgcn_readfirstlane(ee[j]) & 0xFFFFF;
        }
        // Issue all 8 random xb-row gathers up front (the latency killers).
        unsigned short hv[8];
#pragma unroll
        for (int j = 0; j < 8; ++j)
            hv[j] = xb[(size_t)se[j] * C_IN + lane];
        // Attrs + FMA in two 4-edge halves (bounds VGPR pressure).
#pragma unroll
        for (int h4 = 0; h4 < 2; ++h4) {
            float2 a01[4], a23[4], a45[4];
#pragma unroll
            for (int j = 0; j < 4; ++j) {
                const float* eap = ea + (size_t)ee[h4 * 4 + j] * ATTR;
                a01[j] = *(const float2*)(eap + 0);
                a23[j] = *(const float2*)(eap + 2);
                a45[j] = *(const float2*)(eap + 4);
            }
#pragma unroll
            for (int j = 0; j < 4; ++j) {
                const float xvj = __uint_as_float((unsigned)hv[h4 * 4 + j] << 16);
                float s0 = bb[0], s1 = bb[1], s2 = bb[2];
                s0 = fmaf(a01[j].x, w[0][0], s0); s1 = fmaf(a01[j].x, w[0][1], s1); s2 = fmaf(a01[j].x, w[0][2], s2);
                s0 = fmaf(a01[j].y, w[1][0], s0); s1 = fmaf(a01[j].y, w[1][1], s1); s2 = fmaf(a01[j].y, w[1][2], s2);
                s0 = fmaf(a23[j].x, w[2][0], s0); s1 = fmaf(a23[j].x, w[2][1], s1); s2 = fmaf(a23[j].x, w[2][2], s2);
                s0 = fmaf(a23[j].y, w[3][0], s0); s1 = fmaf(a23[j].y, w[3][1], s1); s2 = fmaf(a23[j].y, w[3][2], s2);
                s0 = fmaf(a45[j].x, w[4][0], s0); s1 = fmaf(a45[j].x, w[4][1], s1); s2 = fmaf(a45[j].x, w[4][2], s2);
                s0 = fmaf(a45[j].y, w[5][0], s0); s1 = fmaf(a45[j].y, w[5][1], s1); s2 = fmaf(a45[j].y, w[5][2], s2);
                acc0 = fmaf(fmaxf(s0, 0.f), xvj, acc0);
                acc1 = fmaf(fmaxf(s1, 0.f), xvj, acc1);
                acc2 = fmaf(fmaxf(s2, 0.f), xvj, acc2);
            }
        }
    }
    // fp16 row write (3 shorts/lane, stride-3; agg rows are 384B each).
    _Float16* ap = aggh + (size_t)slot * K3 + col;
    ap[0] = (_Float16)acc0; ap[1] = (_Float16)acc1; ap[2] = (_Float16)acc2;
}

// ---------------------------------------------------------------------------
// phaseC: standalone GEMM [64,192]@[192,128] per (layer, node-group) from
// global fp16 agg (tile L1/L2-hot, broadcast across the 32 threads sharing
// a row group) + bias + tanh + coalesced float4 store. No LDS -> occupancy
// unconstrained; pure VALU-bound.
// ---------------------------------------------------------------------------
__global__ __launch_bounds__(512)
void phaseC(const _Float16* __restrict__ aggh,
            const float* __restrict__ Wo0, const float* __restrict__ bo0,
            const float* __restrict__ Wo1, const float* __restrict__ bo1,
            float* __restrict__ out)
{
    const int t = threadIdx.x;
    const int l = (blockIdx.x >= NBK) ? 1 : 0;
    const int b = blockIdx.x - l * NBK;
    const float* Wo = l ? Wo1 : Wo0;
    const float* bo = l ? bo1 : bo0;

    const int o4 = (t & 31) * 4;
    const int g4 = (t >> 5) * 4;
    const size_t rowbase = (size_t)l * NPAD + (size_t)b * 64 + g4;

    float acc[4][4];
#pragma unroll
    for (int i = 0; i < 4; ++i)
#pragma unroll
        for (int j = 0; j < 4; ++j) acc[i][j] = 0.f;

    for (int k = 0; k < K3; k += 4) {
        const float4 w0 = *(const float4*)(Wo + (size_t)(k + 0) * C_OUTC + o4);
        const float4 w1 = *(const float4*)(Wo + (size_t)(k + 1) * C_OUTC + o4);
        const float4 w2 = *(const float4*)(Wo + (size_t)(k + 2) * C_OUTC + o4);
        const float4 w3 = *(const float4*)(Wo + (size_t)(k + 3) * C_OUTC + o4);
#pragma unroll
        for (int i = 0; i < 4; ++i) {
            const half4v ah = *(const half4v*)(aggh + (rowbase + i) * K3 + k);
            const float ax = (float)ah.x, ay = (float)ah.y;
            const float az = (float)ah.z, aw = (float)ah.w;
            acc[i][0] = fmaf(ax, w0.x, acc[i][0]);
            acc[i][1] = fmaf(ax, w0.y, acc[i][1]);
            acc[i][2] = fmaf(ax, w0.z, acc[i][2]);
            acc[i][3] = fmaf(ax, w0.w, acc[i][3]);
            acc[i][0] = fmaf(ay, w1.x, acc[i][0]);
            acc[i][1] = fmaf(ay, w1.y, acc[i][1]);
            acc[i][2] = fmaf(ay, w1.z, acc[i][2]);
            acc[i][3] = fmaf(ay, w1.w, acc[i][3]);
            acc[i][0] = fmaf(az, w2.x, acc[i][0]);
            acc[i][1] = fmaf(az, w2.y, acc[i][1]);
            acc[i][2] = fmaf(az, w2.z, acc[i][2]);
            acc[i][3] = fmaf(az, w2.w, acc[i][3]);
            acc[i][0] = fmaf(aw, w3.x, acc[i][0]);
            acc[i][1] = fmaf(aw, w3.y, acc[i][1]);
            acc[i][2] = fmaf(aw, w3.z, acc[i][2]);
            acc[i][3] = fmaf(aw, w3.w, acc[i][3]);
        }
    }

    const float4 bias = *(const float4*)(bo + o4);
#pragma unroll
    for (int i = 0; i < 4; ++i) {
        const int node = b * 64 + g4 + i;
        if (node < N_NODES) {
            float4 r;
            r.x = tanhf(acc[i][0] + bias.x);
            r.y = tanhf(acc[i][1] + bias.y);
            r.z = tanhf(acc[i][2] + bias.z);
            r.w = tanhf(acc[i][3] + bias.w);
            *(float4*)(out + (size_t)node * (2 * C_OUTC) + l * C_OUTC + o4) = r;
        }
    }
}

extern "C" void kernel_launch(void* const* d_in, const int* in_sizes, int n_in,
                              void* d_out, int out_size, void* d_ws, size_t ws_size,
                              hipStream_t stream) {
    const float* x   = (const float*)d_in[0];
    const int*   ei0 = (const int*)d_in[1];
    const float* ea0 = (const float*)d_in[2];
    const int*   ei1 = (const int*)d_in[3];
    const float* ea1 = (const float*)d_in[4];
    const float* Wi0 = (const float*)d_in[5];
    const float* bi0 = (const float*)d_in[6];
    const float* Wo0 = (const float*)d_in[7];
    const float* bo0 = (const float*)d_in[8];
    const float* Wi1 = (const float*)d_in[9];
    const float* bi1 = (const float*)d_in[10];
    const float* Wo1 = (const float*)d_in[11];
    const float* bo1 = (const float*)d_in[12];
    float* out = (float*)d_out;

    // Workspace layout (peak 68.0 MB <= 76.8 MB proven):
    //   cursor   : 2048 int                        (8 KB)
    //   row_info : 2*NPAD int2                     (800 KB)
    //   xb       : (N_NODES+1)*C_IN ushort         (6.4 MB, +zero row)
    //   csr      : 2*NBK*CAPP int2                 (22.4 MB)   [end 29.6 MB]
    //   seg      : 2*NBK*CAP int2                  (16.0 MB)   [29.6..45.6]
    //   aggh     : 2*NPAD*K3 fp16                  (38.4 MB)   [29.6..68.0]
    //              aliases seg: seg is dead after pass2, aggh written in phaseB.
    int*  cursor   = (int*)d_ws;
    int2* row_info = (int2*)(cursor + 2048);
    unsigned short* xb = (unsigned short*)(row_info + 2 * NPAD);
    int2* csr      = (int2*)(xb + (size_t)(N_NODES + 1) * C_IN);
    int2* seg      = csr + (size_t)2 * NBK * CAPP;
    _Float16* aggh = (_Float16*)seg;

    hipMemsetAsync(cursor, 0, 2048 * sizeof(int), stream);
    xcvt<<<(XW4Z + 255) / 256, 256, 0, stream>>>(x, xb);
    pass1<<<2 * P1B, 512, 0, stream>>>(ei0, ei1, cursor, seg);
    pass2<<<2 * NBK, 256, 0, stream>>>(cursor, seg, csr, row_info);
    phaseB<<<(2 * NPAD) / 256 * 64, 256, 0, stream>>>(xb, ea0, ea1,
                                                      Wi0, bi0, Wi1, bi1,
                                                      row_info, csr, aggh);
    phaseC<<<2 * NBK, 512, 0, stream>>>(aggh, Wo0, bo0, Wo1, bo1, out);
}

// Round 3
// 373.048 us; speedup vs baseline: 1.3021x; 1.3021x over previous
//
#include <hip/hip_runtime.h>

#define N_NODES 50000
#define N_EDGES 800000
#define C_IN 64
#define HID 3
#define C_OUTC 128
#define ATTR 6
#define K3 192            // HID*C_IN
#define NBK 782           // fine buckets of 64 nodes (dst>>6)
#define NPAD 50048        // NBK*64
#define CAP 1280          // per-bucket seg capacity: mean 1023, +8 sigma
#define CAPP 1792         // per-bucket csr capacity with pad-to-8 (1280+448<=1792, deterministic)
#define EPB 4096          // edges per pass1 block
#define P1B 196           // pass1 blocks per layer

typedef _Float16 half4v __attribute__((ext_vector_type(4)));

// ---------------------------------------------------------------------------
// pass1: bin edges by fine bucket (dst>>6), both layers. (Unchanged.)
// ---------------------------------------------------------------------------
__global__ __launch_bounds__(512)
void pass1(const int* __restrict__ ei0, const int* __restrict__ ei1,
           int* __restrict__ cursor, int2* __restrict__ seg)
{
    __shared__ int s_cnt[NBK], s_ofs[NBK], s_pos[NBK], s_gbase[NBK]; // 12.5 KB
    __shared__ int2 st_es[EPB];                                      // 32 KB
    __shared__ unsigned short st_b[EPB];                             //  8 KB
    __shared__ int wsum[8];
    const int t = threadIdx.x, lane = t & 63, wid = t >> 6;
    const int l = (blockIdx.x >= P1B) ? 1 : 0;
    const int* ei = l ? ei1 : ei0;
    const int base = (blockIdx.x - l * P1B) * EPB;

    for (int i = t; i < NBK; i += 512) s_cnt[i] = 0;
    __syncthreads();

    int src[8], dst[8];
    const int e0 = base + t * 8;
    if (e0 + 7 < N_EDGES) {
        const int4 s0 = *(const int4*)(ei + e0);
        const int4 s1 = *(const int4*)(ei + e0 + 4);
        const int4 d0 = *(const int4*)(ei + N_EDGES + e0);
        const int4 d1 = *(const int4*)(ei + N_EDGES + e0 + 4);
        src[0]=s0.x; src[1]=s0.y; src[2]=s0.z; src[3]=s0.w;
        src[4]=s1.x; src[5]=s1.y; src[6]=s1.z; src[7]=s1.w;
        dst[0]=d0.x; dst[1]=d0.y; dst[2]=d0.z; dst[3]=d0.w;
        dst[4]=d1.x; dst[5]=d1.y; dst[6]=d1.z; dst[7]=d1.w;
    } else {
#pragma unroll
        for (int j = 0; j < 8; ++j) {
            const int e = e0 + j;
            if (e < N_EDGES) { src[j] = ei[e]; dst[j] = ei[N_EDGES + e]; }
            else dst[j] = -1;
        }
    }
#pragma unroll
    for (int j = 0; j < 8; ++j)
        if (dst[j] >= 0) atomicAdd(&s_cnt[dst[j] >> 6], 1);
    __syncthreads();

    // Exclusive block scan of s_cnt[NBK], 2 elements per thread.
    const int i0 = 2 * t, i1 = 2 * t + 1;
    const int v0 = (i0 < NBK) ? s_cnt[i0] : 0;
    const int v1 = (i1 < NBK) ? s_cnt[i1] : 0;
    const int pv = v0 + v1;
    int incl = pv;
#pragma unroll
    for (int off = 1; off < 64; off <<= 1) {
        const int u = __shfl_up(incl, off, 64);
        if (lane >= off) incl += u;
    }
    if (lane == 63) wsum[wid] = incl;
    __syncthreads();
    if (wid == 0) {
        int s = (lane < 8) ? wsum[lane] : 0;
#pragma unroll
        for (int off = 1; off < 8; off <<= 1) {
            const int u = __shfl_up(s, off, 64);
            if (lane >= off) s += u;
        }
        if (lane < 8) wsum[lane] = s;
    }
    __syncthreads();
    const int ex = (wid ? wsum[wid - 1] : 0) + (incl - pv);
    if (i0 < NBK) { s_ofs[i0] = ex;      s_pos[i0] = ex; }
    if (i1 < NBK) { s_ofs[i1] = ex + v0; s_pos[i1] = ex + v0; }
    __syncthreads();

    for (int i = t; i < NBK; i += 512)
        s_gbase[i] = atomicAdd(&cursor[(l << 10) + i], s_cnt[i]);

#pragma unroll
    for (int j = 0; j < 8; ++j) {
        if (dst[j] >= 0) {
            const int b = dst[j] >> 6;
            const int p = atomicAdd(&s_pos[b], 1);
            st_es[p] = make_int2((e0 + j) | ((dst[j] & 63) << 20), src[j]);
            st_b[p]  = (unsigned short)b;
        }
    }
    __syncthreads();

    const int total = (N_EDGES - base < EPB) ? (N_EDGES - base) : EPB;
    for (int j = t; j < total; j += 512) {
        const int b = st_b[j];
        const int g = s_gbase[b] + (j - s_ofs[b]);
        if (g < CAP) seg[(size_t)(l * NBK + b) * CAP + g] = st_es[j];
    }
}

// ---------------------------------------------------------------------------
// pass2: histogram -> padded scan -> node-sorted scatter + sentinel padding.
// (Unchanged.)
// ---------------------------------------------------------------------------
__global__ __launch_bounds__(256)
void pass2(const int* __restrict__ cursor, const int2* __restrict__ seg,
           int2* __restrict__ csr, int2* __restrict__ row_info)
{
    __shared__ int hist[64], cur[64], pex[64];
    const int t = threadIdx.x;
    const int l = (blockIdx.x >= NBK) ? 1 : 0;
    const int fb = blockIdx.x - l * NBK;
    const int S0 = cursor[(l << 10) + fb];
    const int S = (S0 < CAP) ? S0 : CAP;
    const size_t segbase = (size_t)(l * NBK + fb) * CAP;
    const size_t base = (size_t)(l * NBK + fb) * CAPP;
    const int2* segb = seg + segbase;

    if (t < 64) hist[t] = 0;
    __syncthreads();
    for (int i = t; i < S; i += 256)
        atomicAdd(&hist[(segb[i].x >> 20) & 63], 1);
    __syncthreads();

    if (t < 64) {                                             // wave 0 scan
        const int v = hist[t];
        const int pv = (v + 7) & ~7;                          // pad to 8
        int incl = pv;
#pragma unroll
        for (int off = 1; off < 64; off <<= 1) {
            const int u = __shfl_up(incl, off, 64);
            if (t >= off) incl += u;
        }
        const int excl = incl - pv;                           // multiple of 8
        cur[t] = excl;
        pex[t] = excl;
        const int node = fb * 64 + t;
        if (node < N_NODES)
            row_info[l * NPAD + node] = make_int2((int)base + excl, v);
    }
    __syncthreads();

    for (int i = t; i < S; i += 256) {
        const int2 p = segb[i];
        const int dl = (p.x >> 20) & 63;
        const int pos = atomicAdd(&cur[dl], 1);
        csr[base + pos] = p;
    }

    // Fill padding slots (disjoint from scatter region -> no barrier needed).
    if (t < 64) {
        const int v = hist[t];
        const int pv = (v + 7) & ~7;
        for (int p = pex[t] + v; p < pex[t] + pv; ++p)
            csr[base + p] = make_int2(0, N_NODES);            // zero-row sentinel
    }
}

// ---------------------------------------------------------------------------
// xcvt: x fp32 -> bf16 (RNE), plus zeroed sentinel row at index N_NODES.
// ---------------------------------------------------------------------------
#define XW4 ((N_NODES * C_IN) / 4)
#define XW4Z (((N_NODES + 1) * C_IN) / 4)
__global__ __launch_bounds__(256)
void xcvt(const float* __restrict__ x, unsigned short* __restrict__ xb)
{
    const int i = blockIdx.x * 256 + threadIdx.x;             // float4 index
    if (i < XW4) {
        const float4 v = ((const float4*)x)[i];
        ushort4 o;
        unsigned u;
        u = __float_as_uint(v.x); o.x = (unsigned short)((u + 0x7FFF + ((u >> 16) & 1)) >> 16);
        u = __float_as_uint(v.y); o.y = (unsigned short)((u + 0x7FFF + ((u >> 16) & 1)) >> 16);
        u = __float_as_uint(v.z); o.z = (unsigned short)((u + 0x7FFF + ((u >> 16) & 1)) >> 16);
        u = __float_as_uint(v.w); o.w = (unsigned short)((u + 0x7FFF + ((u >> 16) & 1)) >> 16);
        ((ushort4*)xb)[i] = o;
    } else if (i < XW4Z) {
        ((ushort4*)xb)[i] = make_ushort4(0, 0, 0, 0);         // zero row
    }
}

// ---------------------------------------------------------------------------
// mega (fused, R1 structure): one block per (layer, bucket of 64 nodes).
// Phase B: wave-per-node, 8-edge chunks, uniform int4 csr loads, scalarized
// indices, 8 xb gathers in flight. Phase C: GEMM [64,192]@[192,128] + tanh.
// CHANGE vs R1: agg tile in LDS is fp16 (24 KB instead of 48 KB) -> 4
// blocks/CU (32-wave cap) instead of 3, so more independent blocks per CU
// overlap one block's Phase-C FMA with another's Phase-B gather stalls.
// fp16 agg precision proven numerically free in R2 (absmax unchanged).
// ---------------------------------------------------------------------------
__global__ __launch_bounds__(512)
void mega(const unsigned short* __restrict__ xb,
          const float* __restrict__ ea0, const float* __restrict__ ea1,
          const float* __restrict__ Wi0, const float* __restrict__ bi0,
          const float* __restrict__ Wo0, const float* __restrict__ bo0,
          const float* __restrict__ Wi1, const float* __restrict__ bi1,
          const float* __restrict__ Wo1, const float* __restrict__ bo1,
          const int2* __restrict__ row_info, const int2* __restrict__ csr,
          float* __restrict__ out)
{
    __shared__ _Float16 agg[64 * K3];               // 24 KB (fp16)
    const int t = threadIdx.x, lane = t & 63, wv = t >> 6;
    const int l = (blockIdx.x >= NBK) ? 1 : 0;
    const int b = blockIdx.x - l * NBK;
    const float* ea = l ? ea1 : ea0;
    const float* Wi = l ? Wi1 : Wi0;
    const float* bi = l ? bi1 : bi0;
    const float* Wo = l ? Wo1 : Wo0;
    const float* bo = l ? bo1 : bo0;

    const int col = 3 * lane;
    float w[ATTR][HID], bb[HID];
#pragma unroll
    for (int k = 0; k < ATTR; ++k)
#pragma unroll
        for (int h = 0; h < HID; ++h)
            w[k][h] = Wi[k * K3 + col + h];
#pragma unroll
    for (int h = 0; h < HID; ++h) bb[h] = bi[col + h];

    // Preload the wave's 8 row_info entries (8 loads in flight).
    int rbs[8], cns[8];
#pragma unroll
    for (int u = 0; u < 8; ++u) {
        const int node = b * 64 + wv + u * 8;
        int2 ri = make_int2(0, 0);
        if (node < N_NODES) ri = row_info[l * NPAD + node];
        rbs[u] = ri.x; cns[u] = ri.y;
    }

    // Phase B: wave wv owns local nodes wv, wv+8, ..., wv+56.
#pragma unroll 1
    for (int u = 0; u < 8; ++u) {
        const int dl = wv + u * 8;
        const int rb = __builtin_amdgcn_readfirstlane(rbs[u]);
        const int cnt8 = __builtin_amdgcn_readfirstlane((cns[u] + 7) & ~7);
        const int2* __restrict__ ep = csr + rb;      // 64B aligned by construction

        float acc0 = 0.f, acc1 = 0.f, acc2 = 0.f;
        for (int i = 0; i < cnt8; i += 8) {
            // 8 csr entries via 4 uniform 16B loads
            const int4 q0 = *(const int4*)(ep + i + 0);
            const int4 q1 = *(const int4*)(ep + i + 2);
            const int4 q2 = *(const int4*)(ep + i + 4);
            const int4 q3 = *(const int4*)(ep + i + 6);
            int se[8], ee[8];
            se[0] = q0.y; ee[0] = q0.x; se[1] = q0.w; ee[1] = q0.z;
            se[2] = q1.y; ee[2] = q1.x; se[3] = q1.w; ee[3] = q1.z;
            se[4] = q2.y; ee[4] = q2.x; se[5] = q2.w; ee[5] = q2.z;
            se[6] = q3.y; ee[6] = q3.x; se[7] = q3.w; ee[7] = q3.z;
#pragma unroll
            for (int j = 0; j < 8; ++j) {
                se[j] = __builtin_amdgcn_readfirstlane(se[j]);
                ee[j] = __builtin_amdgcn_readfirstlane(ee[j]) & 0xFFFFF;
            }
            // Issue all 8 random xb-row gathers up front (the latency killers).
            unsigned short hv[8];
#pragma unroll
            for (int j = 0; j < 8; ++j)
                hv[j] = xb[(size_t)se[j] * C_IN + lane];
            // Attrs + FMA in two 4-edge halves (bounds VGPR pressure).
#pragma unroll
            for (int h4 = 0; h4 < 2; ++h4) {
                float2 a01[4], a23[4], a45[4];
#pragma unroll
                for (int j = 0; j < 4; ++j) {
                    const float* eap = ea + (size_t)ee[h4 * 4 + j] * ATTR;
                    a01[j] = *(const float2*)(eap + 0);
                    a23[j] = *(const float2*)(eap + 2);
                    a45[j] = *(const float2*)(eap + 4);
                }
#pragma unroll
                for (int j = 0; j < 4; ++j) {
                    const float xvj = __uint_as_float((unsigned)hv[h4 * 4 + j] << 16);
                    float s0 = bb[0], s1 = bb[1], s2 = bb[2];
                    s0 = fmaf(a01[j].x, w[0][0], s0); s1 = fmaf(a01[j].x, w[0][1], s1); s2 = fmaf(a01[j].x, w[0][2], s2);
                    s0 = fmaf(a01[j].y, w[1][0], s0); s1 = fmaf(a01[j].y, w[1][1], s1); s2 = fmaf(a01[j].y, w[1][2], s2);
                    s0 = fmaf(a23[j].x, w[2][0], s0); s1 = fmaf(a23[j].x, w[2][1], s1); s2 = fmaf(a23[j].x, w[2][2], s2);
                    s0 = fmaf(a23[j].y, w[3][0], s0); s1 = fmaf(a23[j].y, w[3][1], s1); s2 = fmaf(a23[j].y, w[3][2], s2);
                    s0 = fmaf(a45[j].x, w[4][0], s0); s1 = fmaf(a45[j].x, w[4][1], s1); s2 = fmaf(a45[j].x, w[4][2], s2);
                    s0 = fmaf(a45[j].y, w[5][0], s0); s1 = fmaf(a45[j].y, w[5][1], s1); s2 = fmaf(a45[j].y, w[5][2], s2);
                    acc0 = fmaf(fmaxf(s0, 0.f), xvj, acc0);
                    acc1 = fmaf(fmaxf(s1, 0.f), xvj, acc1);
                    acc2 = fmaf(fmaxf(s2, 0.f), xvj, acc2);
                }
            }
        }
        // fp16 stores, stride 6B/lane -> worst 2 lanes/bank = free (m136).
        _Float16* ap = &agg[dl * K3 + col];
        ap[0] = (_Float16)acc0; ap[1] = (_Float16)acc1; ap[2] = (_Float16)acc2;
    }
    __syncthreads();

    // Phase C: GEMM from fp16 LDS. thread = 4 nodes x 4 outs; k-step 4.
    // ds_read_b64 at wave-broadcast address: conflict-free.
    const int o4 = (t & 31) * 4;
    const int g4 = (t >> 5) * 4;
    float acc[4][4];
#pragma unroll
    for (int i = 0; i < 4; ++i)
#pragma unroll
        for (int j = 0; j < 4; ++j) acc[i][j] = 0.f;

    for (int k = 0; k < K3; k += 4) {
        const float4 w0 = *(const float4*)(Wo + (size_t)(k + 0) * C_OUTC + o4);
        const float4 w1 = *(const float4*)(Wo + (size_t)(k + 1) * C_OUTC + o4);
        const float4 w2 = *(const float4*)(Wo + (size_t)(k + 2) * C_OUTC + o4);
        const float4 w3 = *(const float4*)(Wo + (size_t)(k + 3) * C_OUTC + o4);
#pragma unroll
        for (int i = 0; i < 4; ++i) {
            const half4v ah = *(const half4v*)(&agg[(g4 + i) * K3 + k]);
            const float ax = (float)ah.x, ay = (float)ah.y;
            const float az = (float)ah.z, aw = (float)ah.w;
            acc[i][0] = fmaf(ax, w0.x, acc[i][0]);
            acc[i][1] = fmaf(ax, w0.y, acc[i][1]);
            acc[i][2] = fmaf(ax, w0.z, acc[i][2]);
            acc[i][3] = fmaf(ax, w0.w, acc[i][3]);
            acc[i][0] = fmaf(ay, w1.x, acc[i][0]);
            acc[i][1] = fmaf(ay, w1.y, acc[i][1]);
            acc[i][2] = fmaf(ay, w1.z, acc[i][2]);
            acc[i][3] = fmaf(ay, w1.w, acc[i][3]);
            acc[i][0] = fmaf(az, w2.x, acc[i][0]);
            acc[i][1] = fmaf(az, w2.y, acc[i][1]);
            acc[i][2] = fmaf(az, w2.z, acc[i][2]);
            acc[i][3] = fmaf(az, w2.w, acc[i][3]);
            acc[i][0] = fmaf(aw, w3.x, acc[i][0]);
            acc[i][1] = fmaf(aw, w3.y, acc[i][1]);
            acc[i][2] = fmaf(aw, w3.z, acc[i][2]);
            acc[i][3] = fmaf(aw, w3.w, acc[i][3]);
        }
    }

    const float4 bias = *(const float4*)(bo + o4);
#pragma unroll
    for (int i = 0; i < 4; ++i) {
        const int node = b * 64 + g4 + i;
        if (node < N_NODES) {
            float4 r;
            r.x = tanhf(acc[i][0] + bias.x);
            r.y = tanhf(acc[i][1] + bias.y);
            r.z = tanhf(acc[i][2] + bias.z);
            r.w = tanhf(acc[i][3] + bias.w);
            *(float4*)(out + (size_t)node * (2 * C_OUTC) + l * C_OUTC + o4) = r;
        }
    }
}

extern "C" void kernel_launch(void* const* d_in, const int* in_sizes, int n_in,
                              void* d_out, int out_size, void* d_ws, size_t ws_size,
                              hipStream_t stream) {
    const float* x   = (const float*)d_in[0];
    const int*   ei0 = (const int*)d_in[1];
    const float* ea0 = (const float*)d_in[2];
    const int*   ei1 = (const int*)d_in[3];
    const float* ea1 = (const float*)d_in[4];
    const float* Wi0 = (const float*)d_in[5];
    const float* bi0 = (const float*)d_in[6];
    const float* Wo0 = (const float*)d_in[7];
    const float* bo0 = (const float*)d_in[8];
    const float* Wi1 = (const float*)d_in[9];
    const float* bi1 = (const float*)d_in[10];
    const float* Wo1 = (const float*)d_in[11];
    const float* bo1 = (const float*)d_in[12];
    float* out = (float*)d_out;

    // Workspace (~45.6 MB; >=76.8 MB proven available):
    //   cursor   : 2048 int                        (8 KB)
    //   row_info : 2*NPAD int2                     (800 KB)
    //   xb       : (N_NODES+1)*C_IN ushort         (6.4 MB, +zero row)
    //   seg      : 2*NBK*CAP  int2                 (16.0 MB)
    //   csr      : 2*NBK*CAPP int2                 (22.4 MB, pad-to-8 runs)
    int*  cursor   = (int*)d_ws;
    int2* row_info = (int2*)(cursor + 2048);
    unsigned short* xb = (unsigned short*)(row_info + 2 * NPAD);
    int2* seg      = (int2*)(xb + (size_t)(N_NODES + 1) * C_IN);
    int2* csr      = seg + (size_t)2 * NBK * CAP;

    hipMemsetAsync(cursor, 0, 2048 * sizeof(int), stream);
    xcvt<<<(XW4Z + 255) / 256, 256, 0, stream>>>(x, xb);
    pass1<<<2 * P1B, 512, 0, stream>>>(ei0, ei1, cursor, seg);
    pass2<<<2 * NBK, 256, 0, stream>>>(cursor, seg, csr, row_info);
    mega<<<2 * NBK, 512, 0, stream>>>(xb, ea0, ea1,
                                      Wi0, bi0, Wo0, bo0,
                                      Wi1, bi1, Wo1, bo1,
                                      row_info, csr, out);
}

// Round 4
// 348.325 us; speedup vs baseline: 1.3945x; 1.0710x over previous
//
#include <hip/hip_runtime.h>

#define N_NODES 50000
#define N_EDGES 800000
#define C_IN 64
#define HID 3
#define C_OUTC 128
#define ATTR 6
#define K3 192            // HID*C_IN
#define NBK 782           // fine buckets of 64 nodes (dst>>6)
#define NPAD 50048        // NBK*64
#define CAP 1280          // per-bucket seg capacity: mean 1023, +8 sigma
#define CAPP 1472         // csr capacity with pad-to-4 (1280 + 64*3 = 1472, exact bound)
#define EPB 4096          // edges per pass1 block
#define P1B 196           // pass1 blocks per layer

typedef _Float16 half4v __attribute__((ext_vector_type(4)));

#define RFL(x) __builtin_amdgcn_readfirstlane((int)(x))

static __device__ __forceinline__ float lo16f(unsigned v) {
    unsigned short s = (unsigned short)(v & 0xFFFF);
    _Float16 h;
    __builtin_memcpy(&h, &s, 2);
    return (float)h;
}
static __device__ __forceinline__ float hi16f(unsigned v) { return lo16f(v >> 16); }

static __device__ __forceinline__ unsigned pkh(float a, float b) {
    _Float16 ha = (_Float16)a, hb = (_Float16)b;
    unsigned short xa, xbits;
    __builtin_memcpy(&xa, &ha, 2);
    __builtin_memcpy(&xbits, &hb, 2);
    return (unsigned)xa | ((unsigned)xbits << 16);
}

// ---------------------------------------------------------------------------
// pass1: bin edges by fine bucket (dst>>6), both layers. (Unchanged.)
// Payload {eid | dstlocal<<20, src}.
// ---------------------------------------------------------------------------
__global__ __launch_bounds__(512)
void pass1(const int* __restrict__ ei0, const int* __restrict__ ei1,
           int* __restrict__ cursor, int2* __restrict__ seg)
{
    __shared__ int s_cnt[NBK], s_ofs[NBK], s_pos[NBK], s_gbase[NBK]; // 12.5 KB
    __shared__ int2 st_es[EPB];                                      // 32 KB
    __shared__ unsigned short st_b[EPB];                             //  8 KB
    __shared__ int wsum[8];
    const int t = threadIdx.x, lane = t & 63, wid = t >> 6;
    const int l = (blockIdx.x >= P1B) ? 1 : 0;
    const int* ei = l ? ei1 : ei0;
    const int base = (blockIdx.x - l * P1B) * EPB;

    for (int i = t; i < NBK; i += 512) s_cnt[i] = 0;
    __syncthreads();

    int src[8], dst[8];
    const int e0 = base + t * 8;
    if (e0 + 7 < N_EDGES) {
        const int4 s0 = *(const int4*)(ei + e0);
        const int4 s1 = *(const int4*)(ei + e0 + 4);
        const int4 d0 = *(const int4*)(ei + N_EDGES + e0);
        const int4 d1 = *(const int4*)(ei + N_EDGES + e0 + 4);
        src[0]=s0.x; src[1]=s0.y; src[2]=s0.z; src[3]=s0.w;
        src[4]=s1.x; src[5]=s1.y; src[6]=s1.z; src[7]=s1.w;
        dst[0]=d0.x; dst[1]=d0.y; dst[2]=d0.z; dst[3]=d0.w;
        dst[4]=d1.x; dst[5]=d1.y; dst[6]=d1.z; dst[7]=d1.w;
    } else {
#pragma unroll
        for (int j = 0; j < 8; ++j) {
            const int e = e0 + j;
            if (e < N_EDGES) { src[j] = ei[e]; dst[j] = ei[N_EDGES + e]; }
            else dst[j] = -1;
        }
    }
#pragma unroll
    for (int j = 0; j < 8; ++j)
        if (dst[j] >= 0) atomicAdd(&s_cnt[dst[j] >> 6], 1);
    __syncthreads();

    // Exclusive block scan of s_cnt[NBK], 2 elements per thread.
    const int i0 = 2 * t, i1 = 2 * t + 1;
    const int v0 = (i0 < NBK) ? s_cnt[i0] : 0;
    const int v1 = (i1 < NBK) ? s_cnt[i1] : 0;
    const int pv = v0 + v1;
    int incl = pv;
#pragma unroll
    for (int off = 1; off < 64; off <<= 1) {
        const int u = __shfl_up(incl, off, 64);
        if (lane >= off) incl += u;
    }
    if (lane == 63) wsum[wid] = incl;
    __syncthreads();
    if (wid == 0) {
        int s = (lane < 8) ? wsum[lane] : 0;
#pragma unroll
        for (int off = 1; off < 8; off <<= 1) {
            const int u = __shfl_up(s, off, 64);
            if (lane >= off) s += u;
        }
        if (lane < 8) wsum[lane] = s;
    }
    __syncthreads();
    const int ex = (wid ? wsum[wid - 1] : 0) + (incl - pv);
    if (i0 < NBK) { s_ofs[i0] = ex;      s_pos[i0] = ex; }
    if (i1 < NBK) { s_ofs[i1] = ex + v0; s_pos[i1] = ex + v0; }
    __syncthreads();

    for (int i = t; i < NBK; i += 512)
        s_gbase[i] = atomicAdd(&cursor[(l << 10) + i], s_cnt[i]);

#pragma unroll
    for (int j = 0; j < 8; ++j) {
        if (dst[j] >= 0) {
            const int b = dst[j] >> 6;
            const int p = atomicAdd(&s_pos[b], 1);
            st_es[p] = make_int2((e0 + j) | ((dst[j] & 63) << 20), src[j]);
            st_b[p]  = (unsigned short)b;
        }
    }
    __syncthreads();

    const int total = (N_EDGES - base < EPB) ? (N_EDGES - base) : EPB;
    for (int j = t; j < total; j += 512) {
        const int b = st_b[j];
        const int g = s_gbase[b] + (j - s_ofs[b]);
        if (g < CAP) seg[(size_t)(l * NBK + b) * CAP + g] = st_es[j];
    }
}

// ---------------------------------------------------------------------------
// pass2: histogram -> pad-to-4 scan -> node-sorted scatter building 16B
// INLINE-ATTR entries {src:int, a0..a5:fp16} (+0-pad). The eid->edge_attr
// gather happens HERE (chain-free, TLP-hidden across 1564 blocks) instead of
// inside mega's latency-critical loop. Padding entries {N_NODES,0,0,0} hit
// the zeroed xb row -> contribute 0.
// ---------------------------------------------------------------------------
__global__ __launch_bounds__(256)
void pass2(const int* __restrict__ cursor, const int2* __restrict__ seg,
           const float* __restrict__ ea0, const float* __restrict__ ea1,
           int4* __restrict__ csr, int2* __restrict__ row_info)
{
    __shared__ int hist[64], cur[64], pex[64];
    const int t = threadIdx.x;
    const int l = (blockIdx.x >= NBK) ? 1 : 0;
    const int fb = blockIdx.x - l * NBK;
    const float* __restrict__ ea = l ? ea1 : ea0;
    const int S0 = cursor[(l << 10) + fb];
    const int S = (S0 < CAP) ? S0 : CAP;
    const size_t segbase = (size_t)(l * NBK + fb) * CAP;
    const size_t base = (size_t)(l * NBK + fb) * CAPP;
    const int2* segb = seg + segbase;

    if (t < 64) hist[t] = 0;
    __syncthreads();
    for (int i = t; i < S; i += 256)
        atomicAdd(&hist[(segb[i].x >> 20) & 63], 1);
    __syncthreads();

    if (t < 64) {                                             // wave 0 scan
        const int v = hist[t];
        const int pv = (v + 3) & ~3;                          // pad to 4
        int incl = pv;
#pragma unroll
        for (int off = 1; off < 64; off <<= 1) {
            const int u = __shfl_up(incl, off, 64);
            if (t >= off) incl += u;
        }
        const int excl = incl - pv;                           // multiple of 4
        cur[t] = excl;
        pex[t] = excl;
        const int node = fb * 64 + t;
        if (node < N_NODES)
            row_info[l * NPAD + node] = make_int2((int)base + excl, v);
    }
    __syncthreads();

    for (int i = t; i < S; i += 256) {
        const int2 p = segb[i];
        const int dl = (p.x >> 20) & 63;
        const int eid = p.x & 0xFFFFF;
        const float2 q01 = *(const float2*)(ea + (size_t)eid * ATTR + 0);
        const float2 q23 = *(const float2*)(ea + (size_t)eid * ATTR + 2);
        const float2 q45 = *(const float2*)(ea + (size_t)eid * ATTR + 4);
        const int pos = atomicAdd(&cur[dl], 1);
        int4 ent;
        ent.x = p.y;                                          // src
        ent.y = (int)pkh(q01.x, q01.y);
        ent.z = (int)pkh(q23.x, q23.y);
        ent.w = (int)pkh(q45.x, q45.y);
        csr[base + pos] = ent;
    }

    // Fill padding slots (disjoint from scatter region -> no barrier needed).
    if (t < 64) {
        const int v = hist[t];
        const int pv = (v + 3) & ~3;
        for (int p = pex[t] + v; p < pex[t] + pv; ++p)
            csr[base + p] = make_int4(N_NODES, 0, 0, 0);      // zero-row sentinel
    }
}

// ---------------------------------------------------------------------------
// xcvt: x fp32 -> bf16 (RNE), plus zeroed sentinel row at index N_NODES.
// ---------------------------------------------------------------------------
#define XW4 ((N_NODES * C_IN) / 4)
#define XW4Z (((N_NODES + 1) * C_IN) / 4)
__global__ __launch_bounds__(256)
void xcvt(const float* __restrict__ x, unsigned short* __restrict__ xb)
{
    const int i = blockIdx.x * 256 + threadIdx.x;             // float4 index
    if (i < XW4) {
        const float4 v = ((const float4*)x)[i];
        ushort4 o;
        unsigned u;
        u = __float_as_uint(v.x); o.x = (unsigned short)((u + 0x7FFF + ((u >> 16) & 1)) >> 16);
        u = __float_as_uint(v.y); o.y = (unsigned short)((u + 0x7FFF + ((u >> 16) & 1)) >> 16);
        u = __float_as_uint(v.z); o.z = (unsigned short)((u + 0x7FFF + ((u >> 16) & 1)) >> 16);
        u = __float_as_uint(v.w); o.w = (unsigned short)((u + 0x7FFF + ((u >> 16) & 1)) >> 16);
        ((ushort4*)xb)[i] = o;
    } else if (i < XW4Z) {
        ((ushort4*)xb)[i] = make_ushort4(0, 0, 0, 0);         // zero row
    }
}

// ---------------------------------------------------------------------------
// mega: 256-thread blocks, 32 nodes each (grid 4*NBK). Wave wv owns nodes
// [wv*8, wv*8+8) of the half-bucket; runs padded to 4 entries.
// Phase B pipeline per run: entry stream is UNIFORM (readfirstlane'd scalars
// -> s_load, lgkm-counted, off the vmcnt path); xb gathers for chunk c are
// issued at the END of iter c and consumed after a full chunk of FMAs in
// iter c+1 (counted vmcnt leaves the next entry load in flight). No eid hop:
// attrs ride inline in the 16B entry. Phase C: [32,192]@[192,128] from fp16
// LDS + bias + tanh.
// ---------------------------------------------------------------------------
#define EDGE_FMA(P0, P1, P2, HJ)                                               \
    {                                                                          \
        const float xv = __uint_as_float((unsigned)(HJ) << 16);                \
        const float A0 = lo16f(P0), A1 = hi16f(P0);                            \
        const float A2 = lo16f(P1), A3 = hi16f(P1);                            \
        const float A4 = lo16f(P2), A5 = hi16f(P2);                            \
        float s0 = bb[0], s1 = bb[1], s2 = bb[2];                              \
        s0 = fmaf(A0, w[0][0], s0); s1 = fmaf(A0, w[0][1], s1); s2 = fmaf(A0, w[0][2], s2); \
        s0 = fmaf(A1, w[1][0], s0); s1 = fmaf(A1, w[1][1], s1); s2 = fmaf(A1, w[1][2], s2); \
        s0 = fmaf(A2, w[2][0], s0); s1 = fmaf(A2, w[2][1], s1); s2 = fmaf(A2, w[2][2], s2); \
        s0 = fmaf(A3, w[3][0], s0); s1 = fmaf(A3, w[3][1], s1); s2 = fmaf(A3, w[3][2], s2); \
        s0 = fmaf(A4, w[4][0], s0); s1 = fmaf(A4, w[4][1], s1); s2 = fmaf(A4, w[4][2], s2); \
        s0 = fmaf(A5, w[5][0], s0); s1 = fmaf(A5, w[5][1], s1); s2 = fmaf(A5, w[5][2], s2); \
        acc0 = fmaf(fmaxf(s0, 0.f), xv, acc0);                                 \
        acc1 = fmaf(fmaxf(s1, 0.f), xv, acc1);                                 \
        acc2 = fmaf(fmaxf(s2, 0.f), xv, acc2);                                 \
    }

__global__ __launch_bounds__(256, 4)
void mega(const unsigned short* __restrict__ xb,
          const float* __restrict__ Wi0, const float* __restrict__ bi0,
          const float* __restrict__ Wo0, const float* __restrict__ bo0,
          const float* __restrict__ Wi1, const float* __restrict__ bi1,
          const float* __restrict__ Wo1, const float* __restrict__ bo1,
          const int2* __restrict__ row_info, const int4* __restrict__ csr,
          float* __restrict__ out)
{
    __shared__ _Float16 agg[32 * K3];               // 12 KB (fp16)
    const int t = threadIdx.x, lane = t & 63, wv = t >> 6;
    const int l = (blockIdx.x >= 2 * NBK) ? 1 : 0;
    const int hb = blockIdx.x - l * 2 * NBK;        // half-bucket 0..2*NBK-1
    const int b = hb >> 1, half = hb & 1;
    const int nodebase = b * 64 + half * 32;
    const float* Wi = l ? Wi1 : Wi0;
    const float* bi = l ? bi1 : bi0;
    const float* Wo = l ? Wo1 : Wo0;
    const float* bo = l ? bo1 : bo0;

    const int col = 3 * lane;
    float w[ATTR][HID], bb[HID];
#pragma unroll
    for (int k = 0; k < ATTR; ++k)
#pragma unroll
        for (int h = 0; h < HID; ++h)
            w[k][h] = Wi[k * K3 + col + h];
#pragma unroll
    for (int h = 0; h < HID; ++h) bb[h] = bi[col + h];

    // Lanes 0..7 hold the wave's 8 runs' row_info (one vector load).
    int2 ri = make_int2(0, 0);
    const int nd = nodebase + wv * 8 + lane;
    if (lane < 8 && nd < N_NODES) ri = row_info[l * NPAD + nd];
    const int riX = ri.x, riY = ri.y;

    // Phase B: wave wv owns local nodes wv*8 .. wv*8+7.
#pragma unroll 1
    for (int u = 0; u < 8; ++u) {
        const int cnt = RFL(__shfl(riY, u));
        const int dl = wv * 8 + u;
        _Float16* ap = &agg[dl * K3 + col];
        if (cnt == 0) {                              // wave-uniform branch
            ap[0] = (_Float16)0.f; ap[1] = (_Float16)0.f; ap[2] = (_Float16)0.f;
            continue;
        }
        const int rb = RFL(__shfl(riX, u));
        const int nch = (cnt + 3) >> 2;              // chunks of 4 (runs padded to 4)
        const int4* __restrict__ ep = csr + rb;

        float acc0 = 0.f, acc1 = 0.f, acc2 = 0.f;

        // --- prologue: chunk 0 ---
        int4 f0 = ep[0], f1 = ep[1], f2 = ep[2], f3 = ep[3];
        int s0_ = RFL(f0.x); unsigned p00 = RFL(f0.y), p01 = RFL(f0.z), p02 = RFL(f0.w);
        int s1_ = RFL(f1.x); unsigned p10 = RFL(f1.y), p11 = RFL(f1.z), p12 = RFL(f1.w);
        int s2_ = RFL(f2.x); unsigned p20 = RFL(f2.y), p21 = RFL(f2.z), p22 = RFL(f2.w);
        int s3_ = RFL(f3.x); unsigned p30 = RFL(f3.y), p31 = RFL(f3.z), p32 = RFL(f3.w);
        unsigned short hv0 = xb[(size_t)(unsigned)s0_ * C_IN + lane];
        unsigned short hv1 = xb[(size_t)(unsigned)s1_ * C_IN + lane];
        unsigned short hv2 = xb[(size_t)(unsigned)s2_ * C_IN + lane];
        unsigned short hv3 = xb[(size_t)(unsigned)s3_ * C_IN + lane];

#pragma unroll 1
        for (int c = 1; c < nch; ++c) {
            // issue next entry loads (uniform -> scalar loads, lgkm path)
            const int4 g0 = ep[4 * c + 0], g1 = ep[4 * c + 1];
            const int4 g2 = ep[4 * c + 2], g3 = ep[4 * c + 3];
            // FMA chunk c-1 (gathers issued last iter; counted wait)
            EDGE_FMA(p00, p01, p02, hv0);
            EDGE_FMA(p10, p11, p12, hv1);
            EDGE_FMA(p20, p21, p22, hv2);
            EDGE_FMA(p30, p31, p32, hv3);
            // rotate in chunk c's scalars (entry loads complete by now)
            s0_ = RFL(g0.x); p00 = RFL(g0.y); p01 = RFL(g0.z); p02 = RFL(g0.w);
            s1_ = RFL(g1.x); p10 = RFL(g1.y); p11 = RFL(g1.z); p12 = RFL(g1.w);
            s2_ = RFL(g2.x); p20 = RFL(g2.y); p21 = RFL(g2.z); p22 = RFL(g2.w);
            s3_ = RFL(g3.x); p30 = RFL(g3.y); p31 = RFL(g3.z); p32 = RFL(g3.w);
            // issue chunk c's gathers (hv regs free after FMAs above)
            hv0 = xb[(size_t)(unsigned)s0_ * C_IN + lane];
            hv1 = xb[(size_t)(unsigned)s1_ * C_IN + lane];
            hv2 = xb[(size_t)(unsigned)s2_ * C_IN + lane];
            hv3 = xb[(size_t)(unsigned)s3_ * C_IN + lane];
        }
        // --- epilogue: last chunk ---
        EDGE_FMA(p00, p01, p02, hv0);
        EDGE_FMA(p10, p11, p12, hv1);
        EDGE_FMA(p20, p21, p22, hv2);
        EDGE_FMA(p30, p31, p32, hv3);

        ap[0] = (_Float16)acc0; ap[1] = (_Float16)acc1; ap[2] = (_Float16)acc2;
    }
    __syncthreads();

    // Phase C: GEMM from fp16 LDS. thread = 4 nodes x 4 outs; k-step 4.
    const int o4 = (t & 31) * 4;
    const int g4 = (t >> 5) * 4;                    // 8 groups x 4 = 32 nodes
    float acc[4][4];
#pragma unroll
    for (int i = 0; i < 4; ++i)
#pragma unroll
        for (int j = 0; j < 4; ++j) acc[i][j] = 0.f;

    for (int k = 0; k < K3; k += 4) {
        const float4 w0 = *(const float4*)(Wo + (size_t)(k + 0) * C_OUTC + o4);
        const float4 w1 = *(const float4*)(Wo + (size_t)(k + 1) * C_OUTC + o4);
        const float4 w2 = *(const float4*)(Wo + (size_t)(k + 2) * C_OUTC + o4);
        const float4 w3 = *(const float4*)(Wo + (size_t)(k + 3) * C_OUTC + o4);
#pragma unroll
        for (int i = 0; i < 4; ++i) {
            const half4v ah = *(const half4v*)(&agg[(g4 + i) * K3 + k]);
            const float ax = (float)ah.x, ay = (float)ah.y;
            const float az = (float)ah.z, aw = (float)ah.w;
            acc[i][0] = fmaf(ax, w0.x, acc[i][0]);
            acc[i][1] = fmaf(ax, w0.y, acc[i][1]);
            acc[i][2] = fmaf(ax, w0.z, acc[i][2]);
            acc[i][3] = fmaf(ax, w0.w, acc[i][3]);
            acc[i][0] = fmaf(ay, w1.x, acc[i][0]);
            acc[i][1] = fmaf(ay, w1.y, acc[i][1]);
            acc[i][2] = fmaf(ay, w1.z, acc[i][2]);
            acc[i][3] = fmaf(ay, w1.w, acc[i][3]);
            acc[i][0] = fmaf(az, w2.x, acc[i][0]);
            acc[i][1] = fmaf(az, w2.y, acc[i][1]);
            acc[i][2] = fmaf(az, w2.z, acc[i][2]);
            acc[i][3] = fmaf(az, w2.w, acc[i][3]);
            acc[i][0] = fmaf(aw, w3.x, acc[i][0]);
            acc[i][1] = fmaf(aw, w3.y, acc[i][1]);
            acc[i][2] = fmaf(aw, w3.z, acc[i][2]);
            acc[i][3] = fmaf(aw, w3.w, acc[i][3]);
        }
    }

    const float4 bias = *(const float4*)(bo + o4);
#pragma unroll
    for (int i = 0; i < 4; ++i) {
        const int node = nodebase + g4 + i;
        if (node < N_NODES) {
            float4 r;
            r.x = tanhf(acc[i][0] + bias.x);
            r.y = tanhf(acc[i][1] + bias.y);
            r.z = tanhf(acc[i][2] + bias.z);
            r.w = tanhf(acc[i][3] + bias.w);
            *(float4*)(out + (size_t)node * (2 * C_OUTC) + l * C_OUTC + o4) = r;
        }
    }
}

extern "C" void kernel_launch(void* const* d_in, const int* in_sizes, int n_in,
                              void* d_out, int out_size, void* d_ws, size_t ws_size,
                              hipStream_t stream) {
    const float* x   = (const float*)d_in[0];
    const int*   ei0 = (const int*)d_in[1];
    const float* ea0 = (const float*)d_in[2];
    const int*   ei1 = (const int*)d_in[3];
    const float* ea1 = (const float*)d_in[4];
    const float* Wi0 = (const float*)d_in[5];
    const float* bi0 = (const float*)d_in[6];
    const float* Wo0 = (const float*)d_in[7];
    const float* bo0 = (const float*)d_in[8];
    const float* Wi1 = (const float*)d_in[9];
    const float* bi1 = (const float*)d_in[10];
    const float* Wo1 = (const float*)d_in[11];
    const float* bo1 = (const float*)d_in[12];
    float* out = (float*)d_out;

    // Workspace (~60.1 MB; >=76.8 MB proven available):
    //   cursor   : 2048 int                        (8 KB)
    //   row_info : 2*NPAD int2                     (800 KB)
    //   xb       : (N_NODES+1)*C_IN ushort         (6.4 MB, +zero row)
    //   seg      : 2*NBK*CAP  int2                 (16.0 MB)
    //   csr      : 2*NBK*CAPP int4                 (36.8 MB, inline fp16 attrs)
    int*  cursor   = (int*)d_ws;
    int2* row_info = (int2*)(cursor + 2048);
    unsigned short* xb = (unsigned short*)(row_info + 2 * NPAD);
    int2* seg      = (int2*)(xb + (size_t)(N_NODES + 1) * C_IN);
    int4* csr      = (int4*)(seg + (size_t)2 * NBK * CAP);

    hipMemsetAsync(cursor, 0, 2048 * sizeof(int), stream);
    xcvt<<<(XW4Z + 255) / 256, 256, 0, stream>>>(x, xb);
    pass1<<<2 * P1B, 512, 0, stream>>>(ei0, ei1, cursor, seg);
    pass2<<<2 * NBK, 256, 0, stream>>>(cursor, seg, ea0, ea1, csr, row_info);
    mega<<<4 * NBK, 256, 0, stream>>>(xb,
                                      Wi0, bi0, Wo0, bo0,
                                      Wi1, bi1, Wo1, bo1,
                                      row_info, csr, out);
}

// Round 5
// 295.134 us; speedup vs baseline: 1.6459x; 1.1802x over previous
//
#include <hip/hip_runtime.h>

#define N_NODES 50000
#define N_EDGES 800000
#define C_IN 64
#define HID 3
#define C_OUTC 128
#define ATTR 6
#define K3 192            // HID*C_IN
#define NBK 782           // fine buckets of 64 nodes (dst>>6)
#define NPAD 50048        // NBK*64
#define CAP 1280          // per-bucket seg capacity: mean 1023, +8 sigma
#define CAPP 1472         // csr capacity with pad-to-4 (1280 + 64*3 = 1472, exact bound)
#define EPB 4096          // edges per pass1 block
#define P1B 196           // pass1 blocks per layer
#define AGS 200           // agg row stride in halves: 400B = 25*16 -> 16B-aligned rows,
                          // bank advance 100 dwords = 4 mod 32 -> conflict-free b128

typedef _Float16 half4v __attribute__((ext_vector_type(4)));
typedef _Float16 half8  __attribute__((ext_vector_type(8)));
typedef float    floatx4 __attribute__((ext_vector_type(4)));

#define RFL(x) __builtin_amdgcn_readfirstlane((int)(x))

static __device__ __forceinline__ float lo16f(unsigned v) {
    unsigned short s = (unsigned short)(v & 0xFFFF);
    _Float16 h;
    __builtin_memcpy(&h, &s, 2);
    return (float)h;
}
static __device__ __forceinline__ float hi16f(unsigned v) { return lo16f(v >> 16); }

static __device__ __forceinline__ unsigned pkh(float a, float b) {
    _Float16 ha = (_Float16)a, hb = (_Float16)b;
    unsigned short xa, xbits;
    __builtin_memcpy(&xa, &ha, 2);
    __builtin_memcpy(&xbits, &hb, 2);
    return (unsigned)xa | ((unsigned)xbits << 16);
}

// ---------------------------------------------------------------------------
// pass1: bin edges by fine bucket (dst>>6), both layers. (Unchanged.)
// Payload {eid | dstlocal<<20, src}.
// ---------------------------------------------------------------------------
__global__ __launch_bounds__(512)
void pass1(const int* __restrict__ ei0, const int* __restrict__ ei1,
           int* __restrict__ cursor, int2* __restrict__ seg)
{
    __shared__ int s_cnt[NBK], s_ofs[NBK], s_pos[NBK], s_gbase[NBK]; // 12.5 KB
    __shared__ int2 st_es[EPB];                                      // 32 KB
    __shared__ unsigned short st_b[EPB];                             //  8 KB
    __shared__ int wsum[8];
    const int t = threadIdx.x, lane = t & 63, wid = t >> 6;
    const int l = (blockIdx.x >= P1B) ? 1 : 0;
    const int* ei = l ? ei1 : ei0;
    const int base = (blockIdx.x - l * P1B) * EPB;

    for (int i = t; i < NBK; i += 512) s_cnt[i] = 0;
    __syncthreads();

    int src[8], dst[8];
    const int e0 = base + t * 8;
    if (e0 + 7 < N_EDGES) {
        const int4 s0 = *(const int4*)(ei + e0);
        const int4 s1 = *(const int4*)(ei + e0 + 4);
        const int4 d0 = *(const int4*)(ei + N_EDGES + e0);
        const int4 d1 = *(const int4*)(ei + N_EDGES + e0 + 4);
        src[0]=s0.x; src[1]=s0.y; src[2]=s0.z; src[3]=s0.w;
        src[4]=s1.x; src[5]=s1.y; src[6]=s1.z; src[7]=s1.w;
        dst[0]=d0.x; dst[1]=d0.y; dst[2]=d0.z; dst[3]=d0.w;
        dst[4]=d1.x; dst[5]=d1.y; dst[6]=d1.z; dst[7]=d1.w;
    } else {
#pragma unroll
        for (int j = 0; j < 8; ++j) {
            const int e = e0 + j;
            if (e < N_EDGES) { src[j] = ei[e]; dst[j] = ei[N_EDGES + e]; }
            else dst[j] = -1;
        }
    }
#pragma unroll
    for (int j = 0; j < 8; ++j)
        if (dst[j] >= 0) atomicAdd(&s_cnt[dst[j] >> 6], 1);
    __syncthreads();

    // Exclusive block scan of s_cnt[NBK], 2 elements per thread.
    const int i0 = 2 * t, i1 = 2 * t + 1;
    const int v0 = (i0 < NBK) ? s_cnt[i0] : 0;
    const int v1 = (i1 < NBK) ? s_cnt[i1] : 0;
    const int pv = v0 + v1;
    int incl = pv;
#pragma unroll
    for (int off = 1; off < 64; off <<= 1) {
        const int u = __shfl_up(incl, off, 64);
        if (lane >= off) incl += u;
    }
    if (lane == 63) wsum[wid] = incl;
    __syncthreads();
    if (wid == 0) {
        int s = (lane < 8) ? wsum[lane] : 0;
#pragma unroll
        for (int off = 1; off < 8; off <<= 1) {
            const int u = __shfl_up(s, off, 64);
            if (lane >= off) s += u;
        }
        if (lane < 8) wsum[lane] = s;
    }
    __syncthreads();
    const int ex = (wid ? wsum[wid - 1] : 0) + (incl - pv);
    if (i0 < NBK) { s_ofs[i0] = ex;      s_pos[i0] = ex; }
    if (i1 < NBK) { s_ofs[i1] = ex + v0; s_pos[i1] = ex + v0; }
    __syncthreads();

    for (int i = t; i < NBK; i += 512)
        s_gbase[i] = atomicAdd(&cursor[(l << 10) + i], s_cnt[i]);

#pragma unroll
    for (int j = 0; j < 8; ++j) {
        if (dst[j] >= 0) {
            const int b = dst[j] >> 6;
            const int p = atomicAdd(&s_pos[b], 1);
            st_es[p] = make_int2((e0 + j) | ((dst[j] & 63) << 20), src[j]);
            st_b[p]  = (unsigned short)b;
        }
    }
    __syncthreads();

    const int total = (N_EDGES - base < EPB) ? (N_EDGES - base) : EPB;
    for (int j = t; j < total; j += 512) {
        const int b = st_b[j];
        const int g = s_gbase[b] + (j - s_ofs[b]);
        if (g < CAP) seg[(size_t)(l * NBK + b) * CAP + g] = st_es[j];
    }
}

// ---------------------------------------------------------------------------
// pass2: histogram -> pad-to-4 scan -> node-sorted scatter building 16B
// INLINE-ATTR entries {src:int, a0..a5:fp16}. (Unchanged.)
// ---------------------------------------------------------------------------
__global__ __launch_bounds__(256)
void pass2(const int* __restrict__ cursor, const int2* __restrict__ seg,
           const float* __restrict__ ea0, const float* __restrict__ ea1,
           int4* __restrict__ csr, int2* __restrict__ row_info)
{
    __shared__ int hist[64], cur[64], pex[64];
    const int t = threadIdx.x;
    const int l = (blockIdx.x >= NBK) ? 1 : 0;
    const int fb = blockIdx.x - l * NBK;
    const float* __restrict__ ea = l ? ea1 : ea0;
    const int S0 = cursor[(l << 10) + fb];
    const int S = (S0 < CAP) ? S0 : CAP;
    const size_t segbase = (size_t)(l * NBK + fb) * CAP;
    const size_t base = (size_t)(l * NBK + fb) * CAPP;
    const int2* segb = seg + segbase;

    if (t < 64) hist[t] = 0;
    __syncthreads();
    for (int i = t; i < S; i += 256)
        atomicAdd(&hist[(segb[i].x >> 20) & 63], 1);
    __syncthreads();

    if (t < 64) {                                             // wave 0 scan
        const int v = hist[t];
        const int pv = (v + 3) & ~3;                          // pad to 4
        int incl = pv;
#pragma unroll
        for (int off = 1; off < 64; off <<= 1) {
            const int u = __shfl_up(incl, off, 64);
            if (t >= off) incl += u;
        }
        const int excl = incl - pv;                           // multiple of 4
        cur[t] = excl;
        pex[t] = excl;
        const int node = fb * 64 + t;
        if (node < N_NODES)
            row_info[l * NPAD + node] = make_int2((int)base + excl, v);
    }
    __syncthreads();

    for (int i = t; i < S; i += 256) {
        const int2 p = segb[i];
        const int dl = (p.x >> 20) & 63;
        const int eid = p.x & 0xFFFFF;
        const float2 q01 = *(const float2*)(ea + (size_t)eid * ATTR + 0);
        const float2 q23 = *(const float2*)(ea + (size_t)eid * ATTR + 2);
        const float2 q45 = *(const float2*)(ea + (size_t)eid * ATTR + 4);
        const int pos = atomicAdd(&cur[dl], 1);
        int4 ent;
        ent.x = p.y;                                          // src
        ent.y = (int)pkh(q01.x, q01.y);
        ent.z = (int)pkh(q23.x, q23.y);
        ent.w = (int)pkh(q45.x, q45.y);
        csr[base + pos] = ent;
    }

    // Fill padding slots (disjoint from scatter region -> no barrier needed).
    if (t < 64) {
        const int v = hist[t];
        const int pv = (v + 3) & ~3;
        for (int p = pex[t] + v; p < pex[t] + pv; ++p)
            csr[base + p] = make_int4(N_NODES, 0, 0, 0);      // zero-row sentinel
    }
}

// ---------------------------------------------------------------------------
// xcvt: x fp32 -> bf16 (RNE), plus zeroed sentinel row at index N_NODES.
// ---------------------------------------------------------------------------
#define XW4 ((N_NODES * C_IN) / 4)
#define XW4Z (((N_NODES + 1) * C_IN) / 4)
__global__ __launch_bounds__(256)
void xcvt(const float* __restrict__ x, unsigned short* __restrict__ xb)
{
    const int i = blockIdx.x * 256 + threadIdx.x;             // float4 index
    if (i < XW4) {
        const float4 v = ((const float4*)x)[i];
        ushort4 o;
        unsigned u;
        u = __float_as_uint(v.x); o.x = (unsigned short)((u + 0x7FFF + ((u >> 16) & 1)) >> 16);
        u = __float_as_uint(v.y); o.y = (unsigned short)((u + 0x7FFF + ((u >> 16) & 1)) >> 16);
        u = __float_as_uint(v.z); o.z = (unsigned short)((u + 0x7FFF + ((u >> 16) & 1)) >> 16);
        u = __float_as_uint(v.w); o.w = (unsigned short)((u + 0x7FFF + ((u >> 16) & 1)) >> 16);
        ((ushort4*)xb)[i] = o;
    } else if (i < XW4Z) {
        ((ushort4*)xb)[i] = make_ushort4(0, 0, 0, 0);         // zero row
    }
}

// ---------------------------------------------------------------------------
// wcvt: Wo fp32 [192][128] -> fp16 packed [k>>3][n][k&7] (both layers), so a
// Phase-C lane's 8 B-fragment halves (contiguous k at fixed n) are one 16B
// coalesced load. K-permutation consistency: both A and B frags use
// "8 contiguous k per lane-group" -> any hw K-order cancels (K = reduction).
// ---------------------------------------------------------------------------
__global__ __launch_bounds__(256)
void wcvt(const float* __restrict__ Wo0, const float* __restrict__ Wo1,
          _Float16* __restrict__ w16)
{
    const int i = blockIdx.x * 256 + threadIdx.x;             // over 2*192*128
    if (i < 2 * K3 * C_OUTC) {
        const int layer = i / (K3 * C_OUTC), r = i % (K3 * C_OUTC);
        const int k = r / C_OUTC, n = r % C_OUTC;
        const float v = (layer ? Wo1 : Wo0)[r];
        w16[((size_t)layer * (K3 / 8) + (k >> 3)) * C_OUTC * 8 + n * 8 + (k & 7)] =
            (_Float16)v;
    }
}

// ---------------------------------------------------------------------------
// mega: 256-thread blocks, 32 nodes each (grid 4*NBK).
// Phase B (unchanged R4 pipeline): wave-per-node runs, uniform 16B entry
// loads + scalarized indices + pipelined xb gathers; fp16 agg rows in LDS
// (stride AGS=200 halves for aligned, conflict-free Phase-C reads).
// Phase C (NEW): [32,192]@[192,128] via v_mfma_f32_16x16x32_f16.
// Wave wv owns rows (wv>>1)*16..+15, cols (wv&1)*64..+63 = 4 N-tiles x 6
// K-steps = 24 MFMA (vs 3072 scalar FMA/thread before). A from LDS
// (ds_read_b128, conflict-free), B from packed fp16 w16 (L2-hot, coalesced).
// D layout (m89-verified): row=(lane>>4)*4+reg, col=lane&15.
// ---------------------------------------------------------------------------
#define EDGE_FMA(P0, P1, P2, HJ)                                               \
    {                                                                          \
        const float xv = __uint_as_float((unsigned)(HJ) << 16);                \
        const float A0 = lo16f(P0), A1 = hi16f(P0);                            \
        const float A2 = lo16f(P1), A3 = hi16f(P1);                            \
        const float A4 = lo16f(P2), A5 = hi16f(P2);                            \
        float s0 = bb[0], s1 = bb[1], s2 = bb[2];                              \
        s0 = fmaf(A0, w[0][0], s0); s1 = fmaf(A0, w[0][1], s1); s2 = fmaf(A0, w[0][2], s2); \
        s0 = fmaf(A1, w[1][0], s0); s1 = fmaf(A1, w[1][1], s1); s2 = fmaf(A1, w[1][2], s2); \
        s0 = fmaf(A2, w[2][0], s0); s1 = fmaf(A2, w[2][1], s1); s2 = fmaf(A2, w[2][2], s2); \
        s0 = fmaf(A3, w[3][0], s0); s1 = fmaf(A3, w[3][1], s1); s2 = fmaf(A3, w[3][2], s2); \
        s0 = fmaf(A4, w[4][0], s0); s1 = fmaf(A4, w[4][1], s1); s2 = fmaf(A4, w[4][2], s2); \
        s0 = fmaf(A5, w[5][0], s0); s1 = fmaf(A5, w[5][1], s1); s2 = fmaf(A5, w[5][2], s2); \
        acc0 = fmaf(fmaxf(s0, 0.f), xv, acc0);                                 \
        acc1 = fmaf(fmaxf(s1, 0.f), xv, acc1);                                 \
        acc2 = fmaf(fmaxf(s2, 0.f), xv, acc2);                                 \
    }

__global__ __launch_bounds__(256, 3)
void mega(const unsigned short* __restrict__ xb,
          const float* __restrict__ Wi0, const float* __restrict__ bi0,
          const float* __restrict__ bo0,
          const float* __restrict__ Wi1, const float* __restrict__ bi1,
          const float* __restrict__ bo1,
          const _Float16* __restrict__ w16,
          const int2* __restrict__ row_info, const int4* __restrict__ csr,
          float* __restrict__ out)
{
    __shared__ __attribute__((aligned(16))) _Float16 agg[32 * AGS];  // 12.5 KB
    const int t = threadIdx.x, lane = t & 63, wv = t >> 6;
    const int l = (blockIdx.x >= 2 * NBK) ? 1 : 0;
    const int hb = blockIdx.x - l * 2 * NBK;        // half-bucket 0..2*NBK-1
    const int b = hb >> 1, half = hb & 1;
    const int nodebase = b * 64 + half * 32;
    const float* Wi = l ? Wi1 : Wi0;
    const float* bi = l ? bi1 : bi0;
    const float* bo = l ? bo1 : bo0;

    const int col = 3 * lane;
    float w[ATTR][HID], bb[HID];
#pragma unroll
    for (int k = 0; k < ATTR; ++k)
#pragma unroll
        for (int h = 0; h < HID; ++h)
            w[k][h] = Wi[k * K3 + col + h];
#pragma unroll
    for (int h = 0; h < HID; ++h) bb[h] = bi[col + h];

    // Lanes 0..7 hold the wave's 8 runs' row_info (one vector load).
    int2 ri = make_int2(0, 0);
    const int nd = nodebase + wv * 8 + lane;
    if (lane < 8 && nd < N_NODES) ri = row_info[l * NPAD + nd];
    const int riX = ri.x, riY = ri.y;

    // Phase B: wave wv owns local nodes wv*8 .. wv*8+7.
#pragma unroll 1
    for (int u = 0; u < 8; ++u) {
        const int cnt = RFL(__shfl(riY, u));
        const int dl = wv * 8 + u;
        _Float16* ap = &agg[dl * AGS + col];
        if (cnt == 0) {                              // wave-uniform branch
            ap[0] = (_Float16)0.f; ap[1] = (_Float16)0.f; ap[2] = (_Float16)0.f;
            continue;
        }
        const int rb = RFL(__shfl(riX, u));
        const int nch = (cnt + 3) >> 2;              // chunks of 4 (runs padded to 4)
        const int4* __restrict__ ep = csr + rb;

        float acc0 = 0.f, acc1 = 0.f, acc2 = 0.f;

        // --- prologue: chunk 0 ---
        int4 f0 = ep[0], f1 = ep[1], f2 = ep[2], f3 = ep[3];
        int s0_ = RFL(f0.x); unsigned p00 = RFL(f0.y), p01 = RFL(f0.z), p02 = RFL(f0.w);
        int s1_ = RFL(f1.x); unsigned p10 = RFL(f1.y), p11 = RFL(f1.z), p12 = RFL(f1.w);
        int s2_ = RFL(f2.x); unsigned p20 = RFL(f2.y), p21 = RFL(f2.z), p22 = RFL(f2.w);
        int s3_ = RFL(f3.x); unsigned p30 = RFL(f3.y), p31 = RFL(f3.z), p32 = RFL(f3.w);
        unsigned short hv0 = xb[(size_t)(unsigned)s0_ * C_IN + lane];
        unsigned short hv1 = xb[(size_t)(unsigned)s1_ * C_IN + lane];
        unsigned short hv2 = xb[(size_t)(unsigned)s2_ * C_IN + lane];
        unsigned short hv3 = xb[(size_t)(unsigned)s3_ * C_IN + lane];

#pragma unroll 1
        for (int c = 1; c < nch; ++c) {
            // issue next entry loads (uniform addresses, stay ahead of drain)
            const int4 g0 = ep[4 * c + 0], g1 = ep[4 * c + 1];
            const int4 g2 = ep[4 * c + 2], g3 = ep[4 * c + 3];
            // FMA chunk c-1 (gathers issued last iter; counted wait)
            EDGE_FMA(p00, p01, p02, hv0);
            EDGE_FMA(p10, p11, p12, hv1);
            EDGE_FMA(p20, p21, p22, hv2);
            EDGE_FMA(p30, p31, p32, hv3);
            // rotate in chunk c's scalars (entry loads complete by now)
            s0_ = RFL(g0.x); p00 = RFL(g0.y); p01 = RFL(g0.z); p02 = RFL(g0.w);
            s1_ = RFL(g1.x); p10 = RFL(g1.y); p11 = RFL(g1.z); p12 = RFL(g1.w);
            s2_ = RFL(g2.x); p20 = RFL(g2.y); p21 = RFL(g2.z); p22 = RFL(g2.w);
            s3_ = RFL(g3.x); p30 = RFL(g3.y); p31 = RFL(g3.z); p32 = RFL(g3.w);
            // issue chunk c's gathers (hv regs free after FMAs above)
            hv0 = xb[(size_t)(unsigned)s0_ * C_IN + lane];
            hv1 = xb[(size_t)(unsigned)s1_ * C_IN + lane];
            hv2 = xb[(size_t)(unsigned)s2_ * C_IN + lane];
            hv3 = xb[(size_t)(unsigned)s3_ * C_IN + lane];
        }
        // --- epilogue: last chunk ---
        EDGE_FMA(p00, p01, p02, hv0);
        EDGE_FMA(p10, p11, p12, hv1);
        EDGE_FMA(p20, p21, p22, hv2);
        EDGE_FMA(p30, p31, p32, hv3);

        ap[0] = (_Float16)acc0; ap[1] = (_Float16)acc1; ap[2] = (_Float16)acc2;
    }
    __syncthreads();

    // Phase C: MFMA GEMM [32,192]@[192,128] from fp16 LDS + packed fp16 Wo.
    const int r0 = (wv >> 1) * 16;                  // row base (nodes)
    const int c0 = (wv & 1) * 64;                   // col base (outputs)
    const int lr = lane & 15, kg = lane >> 4;
    const _Float16* __restrict__ wb = w16 + (size_t)l * (K3 / 8) * C_OUTC * 8;

    floatx4 acc[4];
#pragma unroll
    for (int nt = 0; nt < 4; ++nt) acc[nt] = (floatx4){0.f, 0.f, 0.f, 0.f};

#pragma unroll
    for (int ks = 0; ks < 6; ++ks) {
        const int kb = ks * 32;
        // A-frag: agg row (r0+lr), halves kb + kg*8 .. +7. 16B-aligned:
        // (r0+lr)*400 + kb*2 + kg*16, all multiples of 16. Conflict-free.
        const half8 a = *(const half8*)(&agg[(r0 + lr) * AGS + kb + kg * 8]);
#pragma unroll
        for (int nt = 0; nt < 4; ++nt) {
            const int n = c0 + nt * 16 + lr;
            const half8 bf = *(const half8*)(wb + ((size_t)(ks * 4 + kg) * C_OUTC + n) * 8);
            acc[nt] = __builtin_amdgcn_mfma_f32_16x16x32_f16(a, bf, acc[nt], 0, 0, 0);
        }
    }

#pragma unroll
    for (int nt = 0; nt < 4; ++nt) {
        const int n = c0 + nt * 16 + lr;
        const float bv = bo[n];
#pragma unroll
        for (int r = 0; r < 4; ++r) {
            const int node = nodebase + r0 + kg * 4 + r;
            if (node < N_NODES)
                out[(size_t)node * (2 * C_OUTC) + l * C_OUTC + n] =
                    tanhf(acc[nt][r] + bv);
        }
    }
}

extern "C" void kernel_launch(void* const* d_in, const int* in_sizes, int n_in,
                              void* d_out, int out_size, void* d_ws, size_t ws_size,
                              hipStream_t stream) {
    const float* x   = (const float*)d_in[0];
    const int*   ei0 = (const int*)d_in[1];
    const float* ea0 = (const float*)d_in[2];
    const int*   ei1 = (const int*)d_in[3];
    const float* ea1 = (const float*)d_in[4];
    const float* Wi0 = (const float*)d_in[5];
    const float* bi0 = (const float*)d_in[6];
    const float* Wo0 = (const float*)d_in[7];
    const float* bo0 = (const float*)d_in[8];
    const float* Wi1 = (const float*)d_in[9];
    const float* bi1 = (const float*)d_in[10];
    const float* Wo1 = (const float*)d_in[11];
    const float* bo1 = (const float*)d_in[12];
    float* out = (float*)d_out;

    // Workspace (~60.2 MB; >=76.8 MB proven available):
    //   cursor   : 2048 int                        (8 KB)
    //   row_info : 2*NPAD int2                     (800 KB)
    //   xb       : (N_NODES+1)*C_IN ushort         (6.4 MB, +zero row)
    //   seg      : 2*NBK*CAP  int2                 (16.0 MB)
    //   csr      : 2*NBK*CAPP int4                 (36.8 MB, inline fp16 attrs)
    //   w16      : 2*192*128 fp16                  (96 KB, packed [k/8][n][8])
    int*  cursor   = (int*)d_ws;
    int2* row_info = (int2*)(cursor + 2048);
    unsigned short* xb = (unsigned short*)(row_info + 2 * NPAD);
    int2* seg      = (int2*)(xb + (size_t)(N_NODES + 1) * C_IN);
    int4* csr      = (int4*)(seg + (size_t)2 * NBK * CAP);
    _Float16* w16  = (_Float16*)(csr + (size_t)2 * NBK * CAPP);

    hipMemsetAsync(cursor, 0, 2048 * sizeof(int), stream);
    xcvt<<<(XW4Z + 255) / 256, 256, 0, stream>>>(x, xb);
    wcvt<<<(2 * K3 * C_OUTC + 255) / 256, 256, 0, stream>>>(Wo0, Wo1, w16);
    pass1<<<2 * P1B, 512, 0, stream>>>(ei0, ei1, cursor, seg);
    pass2<<<2 * NBK, 256, 0, stream>>>(cursor, seg, ea0, ea1, csr, row_info);
    mega<<<4 * NBK, 256, 0, stream>>>(xb,
                                      Wi0, bi0, bo0,
                                      Wi1, bi1, bo1,
                                      w16, row_info, csr, out);
}

// Round 6
// 276.135 us; speedup vs baseline: 1.7591x; 1.0688x over previous
//
#include <hip/hip_runtime.h>

#define N_NODES 50000
#define N_EDGES 800000
#define C_IN 64
#define HID 3
#define C_OUTC 128
#define ATTR 6
#define K3 192            // HID*C_IN
#define NREAL 1563        // buckets of 32 nodes (dst>>5): ceil(50000/32)
#define NBK2 1564         // rounded to multiple of 4 for the 4-per-thread scan
#define CAP2 768          // per-bucket capacity: Poisson(512) + 11 sigma
#define EPB2 2048         // edges per pass1 block
#define P1B2 391          // pass1 blocks per layer (391*2048 >= 800000)
#define AGS 200           // agg row stride in halves: 400B = 25*16 -> aligned b128,
                          // bank advance 100 dwords = 4 mod 32 -> conflict-free
#define SORTCAP (CAP2 + 96)   // 768 + 32 nodes * 3 max pad = 864 entries

typedef _Float16 half8  __attribute__((ext_vector_type(8)));
typedef float    floatx4 __attribute__((ext_vector_type(4)));

#define RFL(x) __builtin_amdgcn_readfirstlane((int)(x))

static __device__ __forceinline__ float lo16f(unsigned v) {
    unsigned short s = (unsigned short)(v & 0xFFFF);
    _Float16 h;
    __builtin_memcpy(&h, &s, 2);
    return (float)h;
}
static __device__ __forceinline__ float hi16f(unsigned v) { return lo16f(v >> 16); }

static __device__ __forceinline__ unsigned pkh(float a, float b) {
    _Float16 ha = (_Float16)a, hb = (_Float16)b;
    unsigned short xa, xbits;
    __builtin_memcpy(&xa, &ha, 2);
    __builtin_memcpy(&xbits, &hb, 2);
    return (unsigned)xa | ((unsigned)xbits << 16);
}

// ---------------------------------------------------------------------------
// pass1: bin edges by 32-node bucket (dst>>5), both layers, building the
// FINAL 16B entries {src|dl<<16, a0..a5 fp16}. edge_attr is read HERE,
// sequentially (eid = e0+j) -> coalesced, instead of pass2's random gather.
// LDS staging groups entries by bucket -> coalesced global segment writes.
// src fits 16 bits (50000 < 65536), dl is 5 bits at [20:16].
// ---------------------------------------------------------------------------
__global__ __launch_bounds__(512)
void pass1(const int* __restrict__ ei0, const int* __restrict__ ei1,
           const float* __restrict__ ea0, const float* __restrict__ ea1,
           int* __restrict__ cursor, int4* __restrict__ seg)
{
    __shared__ int s_cnt[NBK2], s_ofs[NBK2], s_pos[NBK2], s_gbase[NBK2]; // 25 KB
    __shared__ int4 st_es[EPB2];                                         // 32 KB
    __shared__ unsigned short st_b[EPB2];                                //  4 KB
    __shared__ int wsum[8];
    const int t = threadIdx.x, lane = t & 63, wid = t >> 6;
    const int l = (blockIdx.x >= P1B2) ? 1 : 0;
    const int* ei = l ? ei1 : ei0;
    const float* __restrict__ ea = l ? ea1 : ea0;
    const int base = (blockIdx.x - l * P1B2) * EPB2;

    for (int i = t; i < NBK2; i += 512) s_cnt[i] = 0;
    __syncthreads();

    int src[4], dst[4];
    unsigned pa0[4], pa1[4], pa2[4];
    const int e0 = base + t * 4;
    if (e0 + 3 < N_EDGES) {
        const int4 s0 = *(const int4*)(ei + e0);
        const int4 d0 = *(const int4*)(ei + N_EDGES + e0);
        src[0]=s0.x; src[1]=s0.y; src[2]=s0.z; src[3]=s0.w;
        dst[0]=d0.x; dst[1]=d0.y; dst[2]=d0.z; dst[3]=d0.w;
#pragma unroll
        for (int j = 0; j < 4; ++j) {
            const float2 q01 = *(const float2*)(ea + (size_t)(e0 + j) * ATTR + 0);
            const float2 q23 = *(const float2*)(ea + (size_t)(e0 + j) * ATTR + 2);
            const float2 q45 = *(const float2*)(ea + (size_t)(e0 + j) * ATTR + 4);
            pa0[j] = pkh(q01.x, q01.y);
            pa1[j] = pkh(q23.x, q23.y);
            pa2[j] = pkh(q45.x, q45.y);
        }
    } else {
#pragma unroll
        for (int j = 0; j < 4; ++j) {
            const int e = e0 + j;
            if (e < N_EDGES) {
                src[j] = ei[e]; dst[j] = ei[N_EDGES + e];
                const float2 q01 = *(const float2*)(ea + (size_t)e * ATTR + 0);
                const float2 q23 = *(const float2*)(ea + (size_t)e * ATTR + 2);
                const float2 q45 = *(const float2*)(ea + (size_t)e * ATTR + 4);
                pa0[j] = pkh(q01.x, q01.y);
                pa1[j] = pkh(q23.x, q23.y);
                pa2[j] = pkh(q45.x, q45.y);
            } else dst[j] = -1;
        }
    }
#pragma unroll
    for (int j = 0; j < 4; ++j)
        if (dst[j] >= 0) atomicAdd(&s_cnt[dst[j] >> 5], 1);
    __syncthreads();

    // Exclusive block scan of s_cnt[NBK2], 4 elements per thread (NBK2 = 4*391).
    int v0 = 0, v1 = 0, v2 = 0, v3 = 0;
    const bool hasq = (t < NBK2 / 4);
    if (hasq) {
        v0 = s_cnt[4 * t + 0]; v1 = s_cnt[4 * t + 1];
        v2 = s_cnt[4 * t + 2]; v3 = s_cnt[4 * t + 3];
    }
    const int pv = v0 + v1 + v2 + v3;
    int incl = pv;
#pragma unroll
    for (int off = 1; off < 64; off <<= 1) {
        const int u = __shfl_up(incl, off, 64);
        if (lane >= off) incl += u;
    }
    if (lane == 63) wsum[wid] = incl;
    __syncthreads();
    if (wid == 0) {
        int s = (lane < 8) ? wsum[lane] : 0;
#pragma unroll
        for (int off = 1; off < 8; off <<= 1) {
            const int u = __shfl_up(s, off, 64);
            if (lane >= off) s += u;
        }
        if (lane < 8) wsum[lane] = s;
    }
    __syncthreads();
    const int ex = (wid ? wsum[wid - 1] : 0) + (incl - pv);
    if (hasq) {
        s_ofs[4 * t + 0] = ex;                s_pos[4 * t + 0] = ex;
        s_ofs[4 * t + 1] = ex + v0;           s_pos[4 * t + 1] = ex + v0;
        s_ofs[4 * t + 2] = ex + v0 + v1;      s_pos[4 * t + 2] = ex + v0 + v1;
        s_ofs[4 * t + 3] = ex + v0 + v1 + v2; s_pos[4 * t + 3] = ex + v0 + v1 + v2;
    }
    __syncthreads();

    for (int i = t; i < NBK2; i += 512)
        if (s_cnt[i]) s_gbase[i] = atomicAdd(&cursor[l * NBK2 + i], s_cnt[i]);

#pragma unroll
    for (int j = 0; j < 4; ++j) {
        if (dst[j] >= 0) {
            const int b = dst[j] >> 5;
            const int p = atomicAdd(&s_pos[b], 1);
            st_es[p] = make_int4(src[j] | ((dst[j] & 31) << 16),
                                 (int)pa0[j], (int)pa1[j], (int)pa2[j]);
            st_b[p]  = (unsigned short)b;
        }
    }
    __syncthreads();

    const int total = (N_EDGES - base < EPB2) ? (N_EDGES - base) : EPB2;
    for (int j = t; j < total; j += 512) {
        const int b = st_b[j];
        const int g = s_gbase[b] + (j - s_ofs[b]);
        if (g < CAP2) seg[(size_t)(l * NREAL + b) * CAP2 + g] = st_es[j];
    }
}

// ---------------------------------------------------------------------------
// xcvt: x fp32 -> bf16 (RNE), plus zeroed sentinel row at index N_NODES.
// ---------------------------------------------------------------------------
#define XW4 ((N_NODES * C_IN) / 4)
#define XW4Z (((N_NODES + 1) * C_IN) / 4)
__global__ __launch_bounds__(256)
void xcvt(const float* __restrict__ x, unsigned short* __restrict__ xb)
{
    const int i = blockIdx.x * 256 + threadIdx.x;             // float4 index
    if (i < XW4) {
        const float4 v = ((const float4*)x)[i];
        ushort4 o;
        unsigned u;
        u = __float_as_uint(v.x); o.x = (unsigned short)((u + 0x7FFF + ((u >> 16) & 1)) >> 16);
        u = __float_as_uint(v.y); o.y = (unsigned short)((u + 0x7FFF + ((u >> 16) & 1)) >> 16);
        u = __float_as_uint(v.z); o.z = (unsigned short)((u + 0x7FFF + ((u >> 16) & 1)) >> 16);
        u = __float_as_uint(v.w); o.w = (unsigned short)((u + 0x7FFF + ((u >> 16) & 1)) >> 16);
        ((ushort4*)xb)[i] = o;
    } else if (i < XW4Z) {
        ((ushort4*)xb)[i] = make_ushort4(0, 0, 0, 0);         // zero row
    }
}

// ---------------------------------------------------------------------------
// wcvt: Wo fp32 [192][128] -> fp16 packed [k>>3][n][k&7] (both layers), so a
// Phase-C lane's 8 B-fragment halves (contiguous k at fixed n) are one 16B
// coalesced load. K-permutation cancels between A and B frags (reduction dim).
// ---------------------------------------------------------------------------
__global__ __launch_bounds__(256)
void wcvt(const float* __restrict__ Wo0, const float* __restrict__ Wo1,
          _Float16* __restrict__ w16)
{
    const int i = blockIdx.x * 256 + threadIdx.x;             // over 2*192*128
    if (i < 2 * K3 * C_OUTC) {
        const int layer = i / (K3 * C_OUTC), r = i % (K3 * C_OUTC);
        const int k = r / C_OUTC, n = r % C_OUTC;
        const float v = (layer ? Wo1 : Wo0)[r];
        w16[((size_t)layer * (K3 / 8) + (k >> 3)) * C_OUTC * 8 + n * 8 + (k & 7)] =
            (_Float16)v;
    }
}

// ---------------------------------------------------------------------------
// mega: one block per (layer, 32-node bucket), 256 threads, grid 2*NREAL.
// Phase A: read the bucket's <=768 entries (3 static regs/thread), LDS
//   histogram over the 32 local nodes, 32-lane scan with pad-to-4, scatter
//   node-sorted into sorted[] LDS + sentinel pads. (Replaces the old pass2.)
// Phase B: wave-per-node runs from LDS (broadcast ds_read, ~120cy, pipelined)
//   + pipelined random xb gathers (the only remaining global dependency).
// Phase C: [32,192]@[192,128] via v_mfma_f32_16x16x32_f16 (unchanged).
// ---------------------------------------------------------------------------
#define EDGE_FMA(P0, P1, P2, HJ)                                               \
    {                                                                          \
        const float xv = __uint_as_float((unsigned)(HJ) << 16);                \
        const float A0 = lo16f(P0), A1 = hi16f(P0);                            \
        const float A2 = lo16f(P1), A3 = hi16f(P1);                            \
        const float A4 = lo16f(P2), A5 = hi16f(P2);                            \
        float s0 = bb[0], s1 = bb[1], s2 = bb[2];                              \
        s0 = fmaf(A0, w[0][0], s0); s1 = fmaf(A0, w[0][1], s1); s2 = fmaf(A0, w[0][2], s2); \
        s0 = fmaf(A1, w[1][0], s0); s1 = fmaf(A1, w[1][1], s1); s2 = fmaf(A1, w[1][2], s2); \
        s0 = fmaf(A2, w[2][0], s0); s1 = fmaf(A2, w[2][1], s1); s2 = fmaf(A2, w[2][2], s2); \
        s0 = fmaf(A3, w[3][0], s0); s1 = fmaf(A3, w[3][1], s1); s2 = fmaf(A3, w[3][2], s2); \
        s0 = fmaf(A4, w[4][0], s0); s1 = fmaf(A4, w[4][1], s1); s2 = fmaf(A4, w[4][2], s2); \
        s0 = fmaf(A5, w[5][0], s0); s1 = fmaf(A5, w[5][1], s1); s2 = fmaf(A5, w[5][2], s2); \
        acc0 = fmaf(fmaxf(s0, 0.f), xv, acc0);                                 \
        acc1 = fmaf(fmaxf(s1, 0.f), xv, acc1);                                 \
        acc2 = fmaf(fmaxf(s2, 0.f), xv, acc2);                                 \
    }

__global__ __launch_bounds__(256, 6)
void mega(const unsigned short* __restrict__ xb,
          const float* __restrict__ Wi0, const float* __restrict__ bi0,
          const float* __restrict__ bo0,
          const float* __restrict__ Wi1, const float* __restrict__ bi1,
          const float* __restrict__ bo1,
          const _Float16* __restrict__ w16,
          const int* __restrict__ cursor, const int4* __restrict__ seg,
          float* __restrict__ out)
{
    __shared__ __attribute__((aligned(16))) int4 sorted[SORTCAP];    // 13824 B
    __shared__ __attribute__((aligned(16))) _Float16 agg[32 * AGS];  // 12800 B
    __shared__ int hist[32], cur[32], pex[32];                       //   384 B
    const int t = threadIdx.x, lane = t & 63, wv = t >> 6;
    const int l = (blockIdx.x >= NREAL) ? 1 : 0;
    const int bk = blockIdx.x - l * NREAL;
    const int nodebase = bk * 32;
    const float* Wi = l ? Wi1 : Wi0;
    const float* bi = l ? bi1 : bi0;
    const float* bo = l ? bo1 : bo0;

    const int col = 3 * lane;
    float w[ATTR][HID], bb[HID];
#pragma unroll
    for (int k = 0; k < ATTR; ++k)
#pragma unroll
        for (int h = 0; h < HID; ++h)
            w[k][h] = Wi[k * K3 + col + h];
#pragma unroll
    for (int h = 0; h < HID; ++h) bb[h] = bi[col + h];

    // ---- Phase A: sort bucket entries by node into LDS ----
    const int S0 = cursor[l * NBK2 + bk];
    const int S = (S0 < CAP2) ? S0 : CAP2;
    const int4* __restrict__ segb = seg + (size_t)(l * NREAL + bk) * CAP2;

    if (t < 32) hist[t] = 0;
    __syncthreads();

    int4 r0 = make_int4(0, 0, 0, 0), r1 = r0, r2 = r0;
    const bool h0 = (t < S), h1 = (t + 256 < S), h2 = (t + 512 < S);
    if (h0) r0 = segb[t];
    if (h1) r1 = segb[t + 256];
    if (h2) r2 = segb[t + 512];
    if (h0) atomicAdd(&hist[(r0.x >> 16) & 31], 1);
    if (h1) atomicAdd(&hist[(r1.x >> 16) & 31], 1);
    if (h2) atomicAdd(&hist[(r2.x >> 16) & 31], 1);
    __syncthreads();

    if (t < 32) {                                  // 32-lane scan, pad-to-4
        const int v = hist[t];
        const int pvv = (v + 3) & ~3;
        int incl = pvv;
#pragma unroll
        for (int off = 1; off < 32; off <<= 1) {
            const int u = __shfl_up(incl, off, 64);
            if (t >= off) incl += u;
        }
        cur[t] = incl - pvv;
        pex[t] = incl - pvv;
    }
    __syncthreads();

    if (h0) sorted[atomicAdd(&cur[(r0.x >> 16) & 31], 1)] = r0;
    if (h1) sorted[atomicAdd(&cur[(r1.x >> 16) & 31], 1)] = r1;
    if (h2) sorted[atomicAdd(&cur[(r2.x >> 16) & 31], 1)] = r2;
    if (t < 32) {                                  // sentinel pads (disjoint)
        const int v = hist[t], pvv = (v + 3) & ~3;
        for (int p = pex[t] + v; p < pex[t] + pvv; ++p)
            sorted[p] = make_int4(N_NODES, 0, 0, 0);
    }
    __syncthreads();

    // ---- Phase B: wave wv owns local nodes wv*8 .. wv*8+7 ----
    int cx = 0, px = 0;
    if (lane < 8) { cx = hist[wv * 8 + lane]; px = pex[wv * 8 + lane]; }

#pragma unroll 1
    for (int u = 0; u < 8; ++u) {
        const int cnt = RFL(__shfl(cx, u));
        const int dl = wv * 8 + u;
        _Float16* ap = &agg[dl * AGS + col];
        if (cnt == 0) {                            // wave-uniform branch
            ap[0] = (_Float16)0.f; ap[1] = (_Float16)0.f; ap[2] = (_Float16)0.f;
            continue;
        }
        const int base = RFL(__shfl(px, u));
        const int nch = (cnt + 3) >> 2;            // runs padded to 4 in LDS
        const int4* __restrict__ ep = &sorted[base];

        float acc0 = 0.f, acc1 = 0.f, acc2 = 0.f;

        // --- prologue: chunk 0 (LDS broadcast reads; values stay in VGPRs) ---
        int4 f0 = ep[0], f1 = ep[1], f2 = ep[2], f3 = ep[3];
        int s0_ = f0.x & 0xFFFF; unsigned p00 = f0.y, p01 = f0.z, p02 = f0.w;
        int s1_ = f1.x & 0xFFFF; unsigned p10 = f1.y, p11 = f1.z, p12 = f1.w;
        int s2_ = f2.x & 0xFFFF; unsigned p20 = f2.y, p21 = f2.z, p22 = f2.w;
        int s3_ = f3.x & 0xFFFF; unsigned p30 = f3.y, p31 = f3.z, p32 = f3.w;
        unsigned short hv0 = xb[(size_t)(unsigned)s0_ * C_IN + lane];
        unsigned short hv1 = xb[(size_t)(unsigned)s1_ * C_IN + lane];
        unsigned short hv2 = xb[(size_t)(unsigned)s2_ * C_IN + lane];
        unsigned short hv3 = xb[(size_t)(unsigned)s3_ * C_IN + lane];

#pragma unroll 1
        for (int c = 1; c < nch; ++c) {
            // issue next chunk's entry reads (LDS, hidden under FMAs below)
            const int4 g0 = ep[4 * c + 0], g1 = ep[4 * c + 1];
            const int4 g2 = ep[4 * c + 2], g3 = ep[4 * c + 3];
            // FMA chunk c-1 (xb gathers issued last iter; counted wait)
            EDGE_FMA(p00, p01, p02, hv0);
            EDGE_FMA(p10, p11, p12, hv1);
            EDGE_FMA(p20, p21, p22, hv2);
            EDGE_FMA(p30, p31, p32, hv3);
            // rotate in chunk c
            s0_ = g0.x & 0xFFFF; p00 = g0.y; p01 = g0.z; p02 = g0.w;
            s1_ = g1.x & 0xFFFF; p10 = g1.y; p11 = g1.z; p12 = g1.w;
            s2_ = g2.x & 0xFFFF; p20 = g2.y; p21 = g2.z; p22 = g2.w;
            s3_ = g3.x & 0xFFFF; p30 = g3.y; p31 = g3.z; p32 = g3.w;
            // issue chunk c's xb gathers
            hv0 = xb[(size_t)(unsigned)s0_ * C_IN + lane];
            hv1 = xb[(size_t)(unsigned)s1_ * C_IN + lane];
            hv2 = xb[(size_t)(unsigned)s2_ * C_IN + lane];
            hv3 = xb[(size_t)(unsigned)s3_ * C_IN + lane];
        }
        // --- epilogue: last chunk ---
        EDGE_FMA(p00, p01, p02, hv0);
        EDGE_FMA(p10, p11, p12, hv1);
        EDGE_FMA(p20, p21, p22, hv2);
        EDGE_FMA(p30, p31, p32, hv3);

        ap[0] = (_Float16)acc0; ap[1] = (_Float16)acc1; ap[2] = (_Float16)acc2;
    }
    __syncthreads();

    // ---- Phase C: MFMA GEMM [32,192]@[192,128] ----
    const int r0r = (wv >> 1) * 16;                 // row base (nodes)
    const int c0 = (wv & 1) * 64;                   // col base (outputs)
    const int lr = lane & 15, kg = lane >> 4;
    const _Float16* __restrict__ wb = w16 + (size_t)l * (K3 / 8) * C_OUTC * 8;

    floatx4 acc[4];
#pragma unroll
    for (int nt = 0; nt < 4; ++nt) acc[nt] = (floatx4){0.f, 0.f, 0.f, 0.f};

#pragma unroll
    for (int ks = 0; ks < 6; ++ks) {
        const int kb = ks * 32;
        const half8 a = *(const half8*)(&agg[(r0r + lr) * AGS + kb + kg * 8]);
#pragma unroll
        for (int nt = 0; nt < 4; ++nt) {
            const int n = c0 + nt * 16 + lr;
            const half8 bf = *(const half8*)(wb + ((size_t)(ks * 4 + kg) * C_OUTC + n) * 8);
            acc[nt] = __builtin_amdgcn_mfma_f32_16x16x32_f16(a, bf, acc[nt], 0, 0, 0);
        }
    }

#pragma unroll
    for (int nt = 0; nt < 4; ++nt) {
        const int n = c0 + nt * 16 + lr;
        const float bv = bo[n];
#pragma unroll
        for (int r = 0; r < 4; ++r) {
            const int node = nodebase + r0r + kg * 4 + r;
            if (node < N_NODES)
                out[(size_t)node * (2 * C_OUTC) + l * C_OUTC + n] =
                    tanhf(acc[nt][r] + bv);
        }
    }
}

extern "C" void kernel_launch(void* const* d_in, const int* in_sizes, int n_in,
                              void* d_out, int out_size, void* d_ws, size_t ws_size,
                              hipStream_t stream) {
    const float* x   = (const float*)d_in[0];
    const int*   ei0 = (const int*)d_in[1];
    const float* ea0 = (const float*)d_in[2];
    const int*   ei1 = (const int*)d_in[3];
    const float* ea1 = (const float*)d_in[4];
    const float* Wi0 = (const float*)d_in[5];
    const float* bi0 = (const float*)d_in[6];
    const float* Wo0 = (const float*)d_in[7];
    const float* bo0 = (const float*)d_in[8];
    const float* Wi1 = (const float*)d_in[9];
    const float* bi1 = (const float*)d_in[10];
    const float* Wo1 = (const float*)d_in[11];
    const float* bo1 = (const float*)d_in[12];
    float* out = (float*)d_out;

    // Workspace (~45 MB; >=76.8 MB proven available):
    //   cursor : 2*NBK2 int                   (12.5 KB)
    //   xb     : (N_NODES+1)*C_IN ushort      (6.4 MB, +zero row)
    //   seg    : 2*NREAL*CAP2 int4            (38.4 MB, inline fp16 attrs)
    //   w16    : 2*192*128 fp16               (96 KB, packed [k/8][n][8])
    int* cursor        = (int*)d_ws;
    unsigned short* xb = (unsigned short*)(cursor + 2 * NBK2);
    int4* seg          = (int4*)(xb + (size_t)(N_NODES + 1) * C_IN);
    _Float16* w16      = (_Float16*)(seg + (size_t)2 * NREAL * CAP2);

    hipMemsetAsync(cursor, 0, 2 * NBK2 * sizeof(int), stream);
    xcvt<<<(XW4Z + 255) / 256, 256, 0, stream>>>(x, xb);
    wcvt<<<(2 * K3 * C_OUTC + 255) / 256, 256, 0, stream>>>(Wo0, Wo1, w16);
    pass1<<<2 * P1B2, 512, 0, stream>>>(ei0, ei1, ea0, ea1, cursor, seg);
    mega<<<2 * NREAL, 256, 0, stream>>>(xb,
                                        Wi0, bi0, bo0,
                                        Wi1, bi1, bo1,
                                        w16, cursor, seg, out);
}